// Round 13
// baseline (1171.342 us; speedup 1.0000x reference)
//
#include <hip/hip_runtime.h>
#include <hip/hip_bf16.h>
#include <math.h>

#define T_STEPS 512
#define BATCH   1024
#define NL2E    (-1.44269504f)   // -log2(e)

typedef __attribute__((ext_vector_type(8))) short short8;
typedef __attribute__((ext_vector_type(4))) float f32x4;

#define MFMA16(A, B, C) __builtin_amdgcn_mfma_f32_16x16x32_bf16((A), (B), (C), 0, 0, 0)

// Prescaled activations: zs = -log2e*z (sigmoid) / -2log2e*z (tanh).
__device__ __forceinline__ float psig(float zs) {
    return __builtin_amdgcn_rcpf(1.0f + __builtin_amdgcn_exp2f(zs));
}
__device__ __forceinline__ float ptanh(float zs) {
    return fmaf(2.0f, __builtin_amdgcn_rcpf(1.0f + __builtin_amdgcn_exp2f(zs)), -1.0f);
}
__device__ __forceinline__ float tanh_c(float c) {   // unprescaled input
    return fmaf(2.0f, __builtin_amdgcn_rcpf(
        1.0f + __builtin_amdgcn_exp2f(2.0f * NL2E * c)), -1.0f);
}
__device__ __forceinline__ unsigned short f2bf(float f) {
    unsigned int u = __float_as_uint(f);
    u += 0x7fffu + ((u >> 16) & 1u);
    return (unsigned short)(u >> 16);
}
// linear k-slot gather with scale folded in before bf16 rounding
__device__ __forceinline__ short8 ldfrag_lin_s(const float* __restrict__ p, float s) {
    short8 r;
#pragma unroll
    for (int e = 0; e < 8; ++e) r[e] = (short)f2bf(p[e] * s);
    return r;
}
// sigma2 gather (k-slot (lg,e) <-> col (e>>2)*16 + lg*4 + (e&3)) with scale
__device__ __forceinline__ short8 ldfrag_s2_s(const float* __restrict__ p, int lg, float s) {
    short8 r;
#pragma unroll
    for (int e = 0; e < 8; ++e) r[e] = (short)f2bf(p[(e >> 2) * 16 + lg * 4 + (e & 3)] * s);
    return r;
}

// ===========================================================================
// K1: layer-1, one wave per (16-batch tile, direction). 128 blocks x 64 thr.
// Whole recurrence in registers (round-5-verified sigma2 scheme): z^T =
// Whh(A, sigma2 frags) x h(B, lane-natural) + [wih|b](A) x [x,1](B).
// 48 MFMA + 16 gate-evals/lane/step. NO barriers, NO LDS in the loop.
// Archive: [tile][t][batch16][unit64] bf16, LIN unit order.
// ===========================================================================
__global__ __launch_bounds__(64, 1) void l1wave_kernel(
    const float* __restrict__ x,
    const float* __restrict__ whh1f, const float* __restrict__ wih1f, const float* __restrict__ b1f,
    const float* __restrict__ whh1r, const float* __restrict__ wih1r, const float* __restrict__ b1r,
    unsigned short* __restrict__ arch_f, unsigned short* __restrict__ arch_r)
{
    __shared__ float xT[T_STEPS][17];
    const int blk = blockIdx.x, dir = blk & 1, tile = blk >> 1;
    const int l = threadIdx.x, lg = l >> 4, lr = l & 15;

    const float* __restrict__ whh = dir ? whh1r : whh1f;
    const float* __restrict__ wih = dir ? wih1r : wih1f;
    const float* __restrict__ bbp = dir ? b1r : b1f;
    unsigned short* __restrict__ ab =
        (dir ? arch_r : arch_f) + (size_t)tile * T_STEPS * 16 * 64;

    for (int i = l; i < T_STEPS * 16; i += 64) {
        const int b = i >> 9, t = i & 511;
        xT[t][b] = x[(size_t)(tile * 16 + b) * T_STEPS + t];
    }

    // m = g*4 + uh (gate-major), rows m*16+lr; lane C rows 4lg+j -> unit uh*16+4lg+j
    short8 WA[16][2], XA[16];
#pragma unroll
    for (int m = 0; m < 16; ++m) {
        const float sf = ((m >> 2) == 2) ? 2.0f * NL2E : NL2E;
        const int row = m * 16 + lr;
        WA[m][0] = ldfrag_s2_s(whh + row * 64, lg, sf);
        WA[m][1] = ldfrag_s2_s(whh + row * 64 + 32, lg, sf);
        short8 xf = {0, 0, 0, 0, 0, 0, 0, 0};
        if (lg == 0) { xf[0] = (short)f2bf(wih[row] * sf); xf[1] = (short)f2bf(bbp[row] * sf); }
        XA[m] = xf;
    }
    float cst[16];
#pragma unroll
    for (int i = 0; i < 16; ++i) cst[i] = 0.f;
    short8 hb0 = {0, 0, 0, 0, 0, 0, 0, 0};
    short8 hb1 = {0, 0, 0, 0, 0, 0, 0, 0};
    __syncthreads();   // xT staging only

    for (int i = 0; i < T_STEPS; ++i) {
        const int t = dir ? (T_STEPS - 1 - i) : i;
        short8 bx = {0, 0, 0, 0, 0, 0, 0, 0};
        if (lg == 0) { bx[0] = (short)f2bf(xT[t][lr]); bx[1] = (short)0x3F80; }  // [x,1]
        f32x4 z[16];
#pragma unroll
        for (int m = 0; m < 16; ++m) {
            f32x4 a = {0.f, 0.f, 0.f, 0.f};
            a = MFMA16(WA[m][0], hb0, a);
            a = MFMA16(WA[m][1], hb1, a);
            a = MFMA16(XA[m], bx, a);
            z[m] = a;
        }
        unsigned short hb[4][4];
#pragma unroll
        for (int uh = 0; uh < 4; ++uh) {
#pragma unroll
            for (int j = 0; j < 4; ++j) {
                const float vi = psig (z[uh][j]);
                const float vf = psig (z[4 + uh][j]);
                const float vg = ptanh(z[8 + uh][j]);
                const float vo = psig (z[12 + uh][j]);
                float& cc = cst[uh * 4 + j];
                cc = fmaf(vf, cc, vi * vg);
                hb[uh][j] = f2bf(vo * tanh_c(cc));
            }
        }
#pragma unroll
        for (int e = 0; e < 8; ++e) {
            hb0[e] = (short)hb[e >> 2][e & 3];        // units  0..31, sigma2 slots
            hb1[e] = (short)hb[2 + (e >> 2)][e & 3];  // units 32..63
        }
#pragma unroll
        for (int uh = 0; uh < 4; ++uh) {
            uint2 v;
            v.x = (unsigned)hb[uh][0] | ((unsigned)hb[uh][1] << 16);
            v.y = (unsigned)hb[uh][2] | ((unsigned)hb[uh][3] << 16);
            *(uint2*)(ab + ((size_t)t * 16 + lr) * 64 + uh * 16 + lg * 4) = v;
        }
    }
}

// ===========================================================================
// K2: layer-2 forward + rev step + head, ONE WAVE per 16-batch tile. 64
// blocks x 64 thr. 8 gate-major M-tiles (rows m*16+lr; tiles 0-1=i, 2-3=f,
// 4-5=g, 6-7=o; lane's unit = (m&1)*16+4lg+j, batch lr). Per step: 8x5 MFMA
// (bias folded into C-init) + 8 gate-evals/lane. h2 B-frag rebuilt in-lane
// (sigma2, round-6-verified pairing with ldfrag_s2(whh2f)). hf/hr from
// archive, 2-step-ahead prefetch in 2 register sets. NO barrier, NO LDS.
// ===========================================================================
__global__ __launch_bounds__(64, 1) void l2wave_kernel(
    const float* __restrict__ wih2f, const float* __restrict__ whh2f, const float* __restrict__ b2f,
    const float* __restrict__ wih2r, const float* __restrict__ b2r,
    const float* __restrict__ w_fc1, const float* __restrict__ b_fc1,
    const float* __restrict__ w_out, const float* __restrict__ b_out,
    const unsigned short* __restrict__ arch_f, const unsigned short* __restrict__ arch_r,
    float* __restrict__ out)
{
    const int bt = blockIdx.x;
    const int l = threadIdx.x, lg = l >> 4, lr = l & 15;
    const unsigned short* __restrict__ af = arch_f + (size_t)bt * T_STEPS * 16 * 64;
    const unsigned short* __restrict__ ar = arch_r + (size_t)bt * T_STEPS * 16 * 64;

    short8 AF[8][4];   // wih2f: [m][0]=hf k0-31, [1]=hf k32-63, [2]=hr k0-31, [3]=hr k32-63
    short8 A2[8];      // whh2f (sigma2)
    f32x4 bz[8];       // bias as C-init
#pragma unroll
    for (int m = 0; m < 8; ++m) {
        const float sf = ((m >> 1) == 2) ? 2.0f * NL2E : NL2E;
        const int row = m * 16 + lr;
        AF[m][0] = ldfrag_lin_s(wih2f + row * 128 + lg * 8, sf);
        AF[m][1] = ldfrag_lin_s(wih2f + row * 128 + 32 + lg * 8, sf);
        AF[m][2] = ldfrag_lin_s(wih2f + row * 128 + 64 + lg * 8, sf);
        AF[m][3] = ldfrag_lin_s(wih2f + row * 128 + 96 + lg * 8, sf);
        A2[m]    = ldfrag_s2_s(whh2f + row * 32, lg, sf);
#pragma unroll
        for (int j = 0; j < 4; ++j) bz[m][j] = b2f[row / 16 * 16 + 4 * lg + j + (m * 16 - row)] ;
        // row/16*16 + ... == m*16 + 4lg + j (row = m*16+lr; bias is per C-row)
#pragma unroll
        for (int j = 0; j < 4; ++j) bz[m][j] = b2f[m * 16 + 4 * lg + j] * sf;
    }

    // 2-step-ahead prefetch, two register sets (A = step s, B = step s+1)
    short8 fA0 = *(const short8*)(af + (size_t)lr * 64 + lg * 8);
    short8 fA1 = *(const short8*)(af + (size_t)lr * 64 + 32 + lg * 8);
    short8 rA0 = *(const short8*)(ar + (size_t)lr * 64 + lg * 8);
    short8 rA1 = *(const short8*)(ar + (size_t)lr * 64 + 32 + lg * 8);
    short8 fB0 = *(const short8*)(af + (size_t)(16 + lr) * 64 + lg * 8);
    short8 fB1 = *(const short8*)(af + (size_t)(16 + lr) * 64 + 32 + lg * 8);
    short8 rB0 = *(const short8*)(ar + (size_t)(16 + lr) * 64 + lg * 8);
    short8 rB1 = *(const short8*)(ar + (size_t)(16 + lr) * 64 + 32 + lg * 8);

    short8 Bh2 = {0, 0, 0, 0, 0, 0, 0, 0};
    float c2[8];
#pragma unroll
    for (int i = 0; i < 8; ++i) c2[i] = 0.f;

    for (int s = 0; s < T_STEPS; ++s) {
        const short8 f0 = fA0, f1 = fA1, r0 = rA0, r1 = rA1;
        fA0 = fB0; fA1 = fB1; rA0 = rB0; rA1 = rB1;
        if (s + 2 < T_STEPS) {
            const size_t o = (size_t)((s + 2) * 16 + lr) * 64 + lg * 8;
            fB0 = *(const short8*)(af + o);
            fB1 = *(const short8*)(af + o + 32);
            rB0 = *(const short8*)(ar + o);
            rB1 = *(const short8*)(ar + o + 32);
        }
        f32x4 z[8];
#pragma unroll
        for (int m = 0; m < 8; ++m) {
            f32x4 a = bz[m];
            a = MFMA16(AF[m][0], f0, a);
            a = MFMA16(AF[m][1], f1, a);
            a = MFMA16(AF[m][2], r0, a);
            a = MFMA16(AF[m][3], r1, a);
            a = MFMA16(A2[m], Bh2, a);
            z[m] = a;
        }
        unsigned short h2b[2][4];
#pragma unroll
        for (int uh = 0; uh < 2; ++uh) {
#pragma unroll
            for (int j = 0; j < 4; ++j) {
                const float vi = psig (z[uh][j]);
                const float vf = psig (z[2 + uh][j]);
                const float vg = ptanh(z[4 + uh][j]);
                const float vo = psig (z[6 + uh][j]);
                float& cc = c2[uh * 4 + j];
                cc = fmaf(vf, cc, vi * vg);
                h2b[uh][j] = f2bf(vo * tanh_c(cc));
            }
        }
#pragma unroll
        for (int e = 0; e < 8; ++e) Bh2[e] = (short)h2b[e >> 2][e & 3];   // sigma2
    }

    // ===== epilogue (same wave): L2-reverse single step @ T-1 + MLP head ===
    {
        short8 Bb = {0, 0, 0, 0, 0, 0, 0, 0};
        if (lg == 0) Bb[0] = (short)0x3F80;                   // B = [1, 0, ...]
        const size_t oL = (size_t)((T_STEPS - 1) * 16 + lr) * 64 + lg * 8;
        const short8 f0 = *(const short8*)(af + oL);
        const short8 f1 = *(const short8*)(af + oL + 32);
        const short8 r0 = *(const short8*)(ar + oL);
        const short8 r1 = *(const short8*)(ar + oL + 32);
        f32x4 ze[8];
#pragma unroll
        for (int mm = 0; mm < 8; ++mm) {
            const int row = mm * 16 + lr;                     // gate-major LIN rows
            const float sfe = ((mm >> 1) == 2) ? 2.0f * NL2E : NL2E;
            const short8 A0 = ldfrag_lin_s(wih2r + row * 128 + lg * 8, sfe);
            const short8 A1 = ldfrag_lin_s(wih2r + row * 128 + 32 + lg * 8, sfe);
            const short8 A2e = ldfrag_lin_s(wih2r + row * 128 + 64 + lg * 8, sfe);
            const short8 A3 = ldfrag_lin_s(wih2r + row * 128 + 96 + lg * 8, sfe);
            short8 bf = {0, 0, 0, 0, 0, 0, 0, 0};
            if (lg == 0) bf[0] = (short)f2bf(b2r[row] * sfe);
            f32x4 za = {0.f, 0.f, 0.f, 0.f}, zb = {0.f, 0.f, 0.f, 0.f};
            za = MFMA16(A0, f0, za);
            za = MFMA16(A2e, r0, za);
            za = MFMA16(bf, Bb, za);
            zb = MFMA16(A1, f1, zb);
            zb = MFMA16(A3, r1, zb);
            ze[mm] = za + zb;
        }
        short8 BR = {0, 0, 0, 0, 0, 0, 0, 0};   // h2r(511), sigma2
#pragma unroll
        for (int uh = 0; uh < 2; ++uh) {
#pragma unroll
            for (int j = 0; j < 4; ++j) {
                const float vi = psig (ze[uh][j]);            // c0=0: f-gate irrelevant
                const float vg = ptanh(ze[4 + uh][j]);
                const float vo = psig (ze[6 + uh][j]);
                BR[uh * 4 + j] = (short)f2bf(vo * tanh_c(vi * vg));
            }
        }
        // head: both w_fc1 halves sigma2-gathered (Bh2 and BR are sigma2)
        float part = 0.f;
#pragma unroll
        for (int mm = 0; mm < 4; ++mm) {
            const int row = mm * 16 + lr;
            const short8 A0 = ldfrag_s2_s(w_fc1 + row * 64, lg, 1.0f);
            const short8 A1 = ldfrag_s2_s(w_fc1 + row * 64 + 32, lg, 1.0f);
            short8 bf = {0, 0, 0, 0, 0, 0, 0, 0};
            if (lg == 0) bf[0] = (short)f2bf(b_fc1[row]);
            f32x4 a = {0.f, 0.f, 0.f, 0.f};
            a = MFMA16(A0, Bh2, a);   // h2f(511)
            a = MFMA16(A1, BR, a);    // h2r(511)
            a = MFMA16(bf, Bb, a);
#pragma unroll
            for (int j = 0; j < 4; ++j)
                part += fmaxf(a[j], 0.f) * w_out[mm * 16 + lg * 4 + j];
        }
        part += __shfl_xor(part, 16, 64);
        part += __shfl_xor(part, 32, 64);
        if (l < 16) out[bt * 16 + lr] = psig(NL2E * (part + b_out[0]));
    }
}

// ---------------------------------------------------------------------------
extern "C" void kernel_launch(void* const* d_in, const int* in_sizes, int n_in,
                              void* d_out, int out_size, void* d_ws, size_t ws_size,
                              hipStream_t stream) {
    const float* x     = (const float*)d_in[0];
    const float* wih1f = (const float*)d_in[1];
    const float* whh1f = (const float*)d_in[2];
    const float* b1f   = (const float*)d_in[3];
    const float* wih1r = (const float*)d_in[4];
    const float* whh1r = (const float*)d_in[5];
    const float* b1r   = (const float*)d_in[6];
    const float* wih2f = (const float*)d_in[7];
    const float* whh2f = (const float*)d_in[8];
    const float* b2f   = (const float*)d_in[9];
    const float* wih2r = (const float*)d_in[10];
    // d_in[11] = whh2r unused: layer-2 reverse runs exactly one step from zero state
    const float* b2r   = (const float*)d_in[12];
    const float* w_fc1 = (const float*)d_in[13];
    const float* b_fc1 = (const float*)d_in[14];
    const float* w_out = (const float*)d_in[15];
    const float* b_out = (const float*)d_in[16];
    float* out = (float*)d_out;

    // 2 x 64 MB archives [tile][t][batch16][unit64] bf16.
    // ws >= 128 MB proven: rounds 8-12 all executed this path.
    unsigned short* arch_f = (unsigned short*)d_ws;
    unsigned short* arch_r = arch_f + (size_t)64 * T_STEPS * 16 * 64;

    l1wave_kernel<<<dim3(128), dim3(64), 0, stream>>>(
        x, whh1f, wih1f, b1f, whh1r, wih1r, b1r, arch_f, arch_r);
    l2wave_kernel<<<dim3(64), dim3(64), 0, stream>>>(
        wih2f, whh2f, b2f, wih2r, b2r,
        w_fc1, b_fc1, w_out, b_out, arch_f, arch_r, out);
}

// Round 14
// 888.010 us; speedup vs baseline: 1.3191x; 1.3191x over previous
//
#include <hip/hip_runtime.h>
#include <hip/hip_bf16.h>
#include <math.h>

#define T_STEPS 512
#define BATCH   1024
#define NL2E    (-1.44269504f)   // -log2(e)

typedef __attribute__((ext_vector_type(8))) short short8;
typedef __attribute__((ext_vector_type(4))) float f32x4;

#define MFMA16(A, B, C) __builtin_amdgcn_mfma_f32_16x16x32_bf16((A), (B), (C), 0, 0, 0)

// LDS-only barrier (round-9-verified safe).
__device__ __forceinline__ void lds_barrier() {
    asm volatile("s_waitcnt lgkmcnt(0)" ::: "memory");
    __builtin_amdgcn_s_barrier();
}

// Prescaled activations: zs = -log2e*z (sigmoid) / -2log2e*z (tanh).
__device__ __forceinline__ float psig(float zs) {
    return __builtin_amdgcn_rcpf(1.0f + __builtin_amdgcn_exp2f(zs));
}
__device__ __forceinline__ float ptanh(float zs) {
    return fmaf(2.0f, __builtin_amdgcn_rcpf(1.0f + __builtin_amdgcn_exp2f(zs)), -1.0f);
}
__device__ __forceinline__ float tanh_c(float c) {   // unprescaled input
    return fmaf(2.0f, __builtin_amdgcn_rcpf(
        1.0f + __builtin_amdgcn_exp2f(2.0f * NL2E * c)), -1.0f);
}
__device__ __forceinline__ unsigned short f2bf(float f) {
    unsigned int u = __float_as_uint(f);
    u += 0x7fffu + ((u >> 16) & 1u);
    return (unsigned short)(u >> 16);
}
// linear k-slot gather with scale folded in before bf16 rounding
__device__ __forceinline__ short8 ldfrag_lin_s(const float* __restrict__ p, float s) {
    short8 r;
#pragma unroll
    for (int e = 0; e < 8; ++e) r[e] = (short)f2bf(p[e] * s);
    return r;
}
__device__ __forceinline__ short8 ldfrag_lin(const float* __restrict__ p) {
    return ldfrag_lin_s(p, 1.0f);
}
// sigma2 gather (k-slot (lg,e) <-> col (e>>2)*16 + lg*4 + (e&3)) with scale
__device__ __forceinline__ short8 ldfrag_s2_s(const float* __restrict__ p, int lg, float s) {
    short8 r;
#pragma unroll
    for (int e = 0; e < 8; ++e) r[e] = (short)f2bf(p[(e >> 2) * 16 + lg * 4 + (e & 3)] * s);
    return r;
}

// ===========================================================================
// K1-dual: layer-1 BOTH directions concurrently. 128 blocks x 256 thr.
// Even blocks: forward -> arch_f; odd: reverse -> arch_r. Weights prescaled
// by -log2e (gates i,f,o) / -2log2e (gate g) at fragment load.
// ROUND-12 VERBATIM (measured ~268 us).
// ===========================================================================
__global__ __launch_bounds__(256, 1) void l1dual_kernel(
    const float* __restrict__ x,
    const float* __restrict__ whh1f, const float* __restrict__ wih1f, const float* __restrict__ b1f,
    const float* __restrict__ whh1r, const float* __restrict__ wih1r, const float* __restrict__ b1r,
    unsigned short* __restrict__ arch_f, unsigned short* __restrict__ arch_r)
{
    __shared__ __align__(16) float xT[T_STEPS][20];
    __shared__ __align__(16) short hT[2][16][72];

    const int blk = blockIdx.x;
    const int dir = blk & 1;            // 0 = fwd, 1 = rev
    const int tile = blk >> 1;
    const int tid = threadIdx.x;
    const int wv = tid >> 6, l = tid & 63, lg = l >> 4, lr = l & 15;

    const float* __restrict__ whh = dir ? whh1r : whh1f;
    const float* __restrict__ wih = dir ? wih1r : wih1f;
    const float* __restrict__ bbp = dir ? b1r : b1f;
    unsigned short* __restrict__ archb =
        (dir ? arch_r : arch_f) + (size_t)tile * T_STEPS * 16 * 64;

    for (int i = tid; i < T_STEPS * 16; i += 256) {
        const int b = i >> 9, t = i & 511;
        xT[t][b] = x[(size_t)(tile * 16 + b) * T_STEPS + t];
    }
    for (int i = tid; i < 2 * 16 * 72; i += 256) ((short*)hT)[i] = 0;

    short8 BW[8]; float wihv[4], bvv[4];
#pragma unroll
    for (int g = 0; g < 4; ++g) {
        const float sf = (g == 2) ? 2.0f * NL2E : NL2E;
        const int row = g * 64 + wv * 16 + lr;
        BW[2 * g]     = ldfrag_lin_s(whh + row * 64 + lg * 8, sf);
        BW[2 * g + 1] = ldfrag_lin_s(whh + row * 64 + 32 + lg * 8, sf);
        wihv[g] = wih[row] * sf; bvv[g] = bbp[row] * sf;
    }
    float cst[4] = {0.f, 0.f, 0.f, 0.f};
    __syncthreads();

    for (int i = 0; i < T_STEPS; ++i) {
        const int t = dir ? (T_STEPS - 1 - i) : i;
        const int rp = (t + 1) & 1;     // parity of previous step (both dirs)
        const short8 a0 = *(const short8*)&hT[rp][lr][lg * 8];
        const short8 a1 = *(const short8*)&hT[rp][lr][32 + lg * 8];
        f32x4 z[4];
#pragma unroll
        for (int g = 0; g < 4; ++g) {
            f32x4 za = {0.f, 0.f, 0.f, 0.f}, zb = {0.f, 0.f, 0.f, 0.f};
            za = MFMA16(a0, BW[2 * g], za);
            zb = MFMA16(a1, BW[2 * g + 1], zb);
            z[g] = za + zb;
        }
        const float4 x4v = *(const float4*)&xT[t][lg * 4];
        const float xa[4] = {x4v.x, x4v.y, x4v.z, x4v.w};
#pragma unroll
        for (int j = 0; j < 4; ++j) {
            const float vi = psig (z[0][j] + fmaf(xa[j], wihv[0], bvv[0]));
            const float vf = psig (z[1][j] + fmaf(xa[j], wihv[1], bvv[1]));
            const float vg = ptanh(z[2][j] + fmaf(xa[j], wihv[2], bvv[2]));
            const float vo = psig (z[3][j] + fmaf(xa[j], wihv[3], bvv[3]));
            cst[j] = fmaf(vf, cst[j], vi * vg);
            const float h = vo * tanh_c(cst[j]);
            const unsigned short hb = f2bf(h);
            hT[t & 1][lg * 4 + j][wv * 16 + lr] = (short)hb;
            archb[((size_t)t * 16 + lg * 4 + j) * 64 + wv * 16 + lr] = hb;
        }
        lds_barrier();
    }
}

// ===========================================================================
// K2: layer-2 forward + rev step + head, ONE WAVE per 16-batch tile
// (round-13 structure: barrier-free, beat the 8-wave version) + SOFTWARE
// PIPELINE (from l2top): critical path per step is only
//   z[m] = MFMA(A2[m], Bh2, zpre[m])   (8 independent MFMAs) -> gates,
// while zpre(s+1) = bz + 4 AF-MFMAs per m (32 MFMA, inputs prefetched from
// the archives) issues OFF-path, overlapping the gate trans phase (separate
// pipes). 64 blocks x 64 thr.
// ===========================================================================
__global__ __launch_bounds__(64, 1) void l2wave_kernel(
    const float* __restrict__ wih2f, const float* __restrict__ whh2f, const float* __restrict__ b2f,
    const float* __restrict__ wih2r, const float* __restrict__ b2r,
    const float* __restrict__ w_fc1, const float* __restrict__ b_fc1,
    const float* __restrict__ w_out, const float* __restrict__ b_out,
    const unsigned short* __restrict__ arch_f, const unsigned short* __restrict__ arch_r,
    float* __restrict__ out)
{
    const int bt = blockIdx.x;
    const int l = threadIdx.x, lg = l >> 4, lr = l & 15;
    const unsigned short* __restrict__ af = arch_f + (size_t)bt * T_STEPS * 16 * 64;
    const unsigned short* __restrict__ ar = arch_r + (size_t)bt * T_STEPS * 16 * 64;

    short8 AF[8][4];   // wih2f: [m][0]=hf k0-31, [1]=hf k32-63, [2]=hr k0-31, [3]=hr k32-63
    short8 A2[8];      // whh2f (sigma2)
    f32x4 bz[8];       // bias as C-init
#pragma unroll
    for (int m = 0; m < 8; ++m) {
        const float sf = ((m >> 1) == 2) ? 2.0f * NL2E : NL2E;
        const int row = m * 16 + lr;
        AF[m][0] = ldfrag_lin_s(wih2f + row * 128 + lg * 8, sf);
        AF[m][1] = ldfrag_lin_s(wih2f + row * 128 + 32 + lg * 8, sf);
        AF[m][2] = ldfrag_lin_s(wih2f + row * 128 + 64 + lg * 8, sf);
        AF[m][3] = ldfrag_lin_s(wih2f + row * 128 + 96 + lg * 8, sf);
        A2[m]    = ldfrag_s2_s(whh2f + row * 32, lg, sf);
#pragma unroll
        for (int j = 0; j < 4; ++j) bz[m][j] = b2f[m * 16 + 4 * lg + j] * sf;
    }

    // ---- pipeline prologue ----
    // zpre(0) from directly-loaded frags(0); fA = frags(1); fB <- frags(2).
    f32x4 zpre[8];
    {
        const short8 f0 = *(const short8*)(af + (size_t)lr * 64 + lg * 8);
        const short8 f1 = *(const short8*)(af + (size_t)lr * 64 + 32 + lg * 8);
        const short8 r0 = *(const short8*)(ar + (size_t)lr * 64 + lg * 8);
        const short8 r1 = *(const short8*)(ar + (size_t)lr * 64 + 32 + lg * 8);
#pragma unroll
        for (int m = 0; m < 8; ++m) {
            f32x4 a = bz[m], b = {0.f, 0.f, 0.f, 0.f};
            a = MFMA16(AF[m][0], f0, a);
            a = MFMA16(AF[m][2], r0, a);
            b = MFMA16(AF[m][1], f1, b);
            b = MFMA16(AF[m][3], r1, b);
            zpre[m] = a + b;
        }
    }
    short8 fA0 = *(const short8*)(af + (size_t)(16 + lr) * 64 + lg * 8);
    short8 fA1 = *(const short8*)(af + (size_t)(16 + lr) * 64 + 32 + lg * 8);
    short8 rA0 = *(const short8*)(ar + (size_t)(16 + lr) * 64 + lg * 8);
    short8 rA1 = *(const short8*)(ar + (size_t)(16 + lr) * 64 + 32 + lg * 8);
    short8 fB0 = *(const short8*)(af + (size_t)(2 * 16 + lr) * 64 + lg * 8);
    short8 fB1 = *(const short8*)(af + (size_t)(2 * 16 + lr) * 64 + 32 + lg * 8);
    short8 rB0 = *(const short8*)(ar + (size_t)(2 * 16 + lr) * 64 + lg * 8);
    short8 rB1 = *(const short8*)(ar + (size_t)(2 * 16 + lr) * 64 + 32 + lg * 8);

    short8 Bh2 = {0, 0, 0, 0, 0, 0, 0, 0};
    float c2[8];
#pragma unroll
    for (int i = 0; i < 8; ++i) c2[i] = 0.f;

    for (int s = 0; s < T_STEPS; ++s) {
        // ---- critical path: z(s) = zpre(s) + Whh2.h2(s-1); 8 indep MFMAs
        f32x4 z[8];
#pragma unroll
        for (int m = 0; m < 8; ++m) z[m] = MFMA16(A2[m], Bh2, zpre[m]);
        // ---- off-path: zpre(s+1) from fA frags (independent of z/Bh2) ----
#pragma unroll
        for (int m = 0; m < 8; ++m) {
            f32x4 a = bz[m], b = {0.f, 0.f, 0.f, 0.f};
            a = MFMA16(AF[m][0], fA0, a);
            a = MFMA16(AF[m][2], rA0, a);
            b = MFMA16(AF[m][1], fA1, b);
            b = MFMA16(AF[m][3], rA1, b);
            zpre[m] = a + b;
        }
        // rotate prefetch regs; issue loads for frags(s+3)
        fA0 = fB0; fA1 = fB1; rA0 = rB0; rA1 = rB1;
        if (s + 3 < T_STEPS) {
            const size_t o = (size_t)((s + 3) * 16 + lr) * 64 + lg * 8;
            fB0 = *(const short8*)(af + o);
            fB1 = *(const short8*)(af + o + 32);
            rB0 = *(const short8*)(ar + o);
            rB1 = *(const short8*)(ar + o + 32);
        }
        // ---- gates (trans phase; off-path MFMAs overlap this) ----
        unsigned short h2b[2][4];
#pragma unroll
        for (int uh = 0; uh < 2; ++uh) {
#pragma unroll
            for (int j = 0; j < 4; ++j) {
                const float vi = psig (z[uh][j]);
                const float vf = psig (z[2 + uh][j]);
                const float vg = ptanh(z[4 + uh][j]);
                const float vo = psig (z[6 + uh][j]);
                float& cc = c2[uh * 4 + j];
                cc = fmaf(vf, cc, vi * vg);
                h2b[uh][j] = f2bf(vo * tanh_c(cc));
            }
        }
#pragma unroll
        for (int e = 0; e < 8; ++e) Bh2[e] = (short)h2b[e >> 2][e & 3];   // sigma2
    }

    // ===== epilogue (same wave): L2-reverse single step @ T-1 + MLP head ===
    {
        short8 Bb = {0, 0, 0, 0, 0, 0, 0, 0};
        if (lg == 0) Bb[0] = (short)0x3F80;                   // B = [1, 0, ...]
        const size_t oL = (size_t)((T_STEPS - 1) * 16 + lr) * 64 + lg * 8;
        const short8 f0 = *(const short8*)(af + oL);
        const short8 f1 = *(const short8*)(af + oL + 32);
        const short8 r0 = *(const short8*)(ar + oL);
        const short8 r1 = *(const short8*)(ar + oL + 32);
        f32x4 ze[8];
#pragma unroll
        for (int mm = 0; mm < 8; ++mm) {
            const int row = mm * 16 + lr;                     // gate-major LIN rows
            const float sfe = ((mm >> 1) == 2) ? 2.0f * NL2E : NL2E;
            const short8 A0 = ldfrag_lin_s(wih2r + row * 128 + lg * 8, sfe);
            const short8 A1 = ldfrag_lin_s(wih2r + row * 128 + 32 + lg * 8, sfe);
            const short8 A2e = ldfrag_lin_s(wih2r + row * 128 + 64 + lg * 8, sfe);
            const short8 A3 = ldfrag_lin_s(wih2r + row * 128 + 96 + lg * 8, sfe);
            short8 bf = {0, 0, 0, 0, 0, 0, 0, 0};
            if (lg == 0) bf[0] = (short)f2bf(b2r[row] * sfe);
            f32x4 za = {0.f, 0.f, 0.f, 0.f}, zb = {0.f, 0.f, 0.f, 0.f};
            za = MFMA16(A0, f0, za);
            za = MFMA16(A2e, r0, za);
            za = MFMA16(bf, Bb, za);
            zb = MFMA16(A1, f1, zb);
            zb = MFMA16(A3, r1, zb);
            ze[mm] = za + zb;
        }
        short8 BR = {0, 0, 0, 0, 0, 0, 0, 0};   // h2r(511), sigma2
#pragma unroll
        for (int uh = 0; uh < 2; ++uh) {
#pragma unroll
            for (int j = 0; j < 4; ++j) {
                const float vi = psig (ze[uh][j]);            // c0=0: f-gate irrelevant
                const float vg = ptanh(ze[4 + uh][j]);
                const float vo = psig (ze[6 + uh][j]);
                BR[uh * 4 + j] = (short)f2bf(vo * tanh_c(vi * vg));
            }
        }
        // head: both w_fc1 halves sigma2-gathered (Bh2 and BR are sigma2)
        float part = 0.f;
#pragma unroll
        for (int mm = 0; mm < 4; ++mm) {
            const int row = mm * 16 + lr;
            const short8 A0 = ldfrag_s2_s(w_fc1 + row * 64, lg, 1.0f);
            const short8 A1 = ldfrag_s2_s(w_fc1 + row * 64 + 32, lg, 1.0f);
            short8 bf = {0, 0, 0, 0, 0, 0, 0, 0};
            if (lg == 0) bf[0] = (short)f2bf(b_fc1[row]);
            f32x4 a = {0.f, 0.f, 0.f, 0.f};
            a = MFMA16(A0, Bh2, a);   // h2f(511)
            a = MFMA16(A1, BR, a);    // h2r(511)
            a = MFMA16(bf, Bb, a);
#pragma unroll
            for (int j = 0; j < 4; ++j)
                part += fmaxf(a[j], 0.f) * w_out[mm * 16 + lg * 4 + j];
        }
        part += __shfl_xor(part, 16, 64);
        part += __shfl_xor(part, 32, 64);
        if (l < 16) out[bt * 16 + lr] = psig(NL2E * (part + b_out[0]));
    }
}

// ---------------------------------------------------------------------------
extern "C" void kernel_launch(void* const* d_in, const int* in_sizes, int n_in,
                              void* d_out, int out_size, void* d_ws, size_t ws_size,
                              hipStream_t stream) {
    const float* x     = (const float*)d_in[0];
    const float* wih1f = (const float*)d_in[1];
    const float* whh1f = (const float*)d_in[2];
    const float* b1f   = (const float*)d_in[3];
    const float* wih1r = (const float*)d_in[4];
    const float* whh1r = (const float*)d_in[5];
    const float* b1r   = (const float*)d_in[6];
    const float* wih2f = (const float*)d_in[7];
    const float* whh2f = (const float*)d_in[8];
    const float* b2f   = (const float*)d_in[9];
    const float* wih2r = (const float*)d_in[10];
    // d_in[11] = whh2r unused: layer-2 reverse runs exactly one step from zero state
    const float* b2r   = (const float*)d_in[12];
    const float* w_fc1 = (const float*)d_in[13];
    const float* b_fc1 = (const float*)d_in[14];
    const float* w_out = (const float*)d_in[15];
    const float* b_out = (const float*)d_in[16];
    float* out = (float*)d_out;

    // 2 x 64 MB archives [tile][t][batch16][unit64] bf16 (ws >= 128 MB proven).
    unsigned short* arch_f = (unsigned short*)d_ws;
    unsigned short* arch_r = arch_f + (size_t)64 * T_STEPS * 16 * 64;

    l1dual_kernel<<<dim3(128), dim3(256), 0, stream>>>(
        x, whh1f, wih1f, b1f, whh1r, wih1r, b1r, arch_f, arch_r);
    l2wave_kernel<<<dim3(64), dim3(64), 0, stream>>>(
        wih2f, whh2f, b2f, wih2r, b2r,
        w_fc1, b_fc1, w_out, b_out, arch_f, arch_r, out);
}

// Round 15
// 752.485 us; speedup vs baseline: 1.5566x; 1.1801x over previous
//
#include <hip/hip_runtime.h>
#include <hip/hip_bf16.h>
#include <math.h>

#define T_STEPS 512
#define BATCH   1024
#define NL2E    (-1.44269504f)   // -log2(e)

typedef __attribute__((ext_vector_type(8))) short short8;
typedef __attribute__((ext_vector_type(4))) float f32x4;

#define MFMA16(A, B, C) __builtin_amdgcn_mfma_f32_16x16x32_bf16((A), (B), (C), 0, 0, 0)

// LDS-only barrier (round-9-verified safe).
__device__ __forceinline__ void lds_barrier() {
    asm volatile("s_waitcnt lgkmcnt(0)" ::: "memory");
    __builtin_amdgcn_s_barrier();
}

// Prescaled activations: zs = -log2e*z (sigmoid) / -2log2e*z (tanh).
__device__ __forceinline__ float psig(float zs) {
    return __builtin_amdgcn_rcpf(1.0f + __builtin_amdgcn_exp2f(zs));
}
__device__ __forceinline__ float ptanh(float zs) {
    return fmaf(2.0f, __builtin_amdgcn_rcpf(1.0f + __builtin_amdgcn_exp2f(zs)), -1.0f);
}
__device__ __forceinline__ float tanh_c(float c) {   // unprescaled input
    return fmaf(2.0f, __builtin_amdgcn_rcpf(
        1.0f + __builtin_amdgcn_exp2f(2.0f * NL2E * c)), -1.0f);
}
__device__ __forceinline__ unsigned short f2bf(float f) {
    unsigned int u = __float_as_uint(f);
    u += 0x7fffu + ((u >> 16) & 1u);
    return (unsigned short)(u >> 16);
}
// linear k-slot gather with scale folded in before bf16 rounding
__device__ __forceinline__ short8 ldfrag_lin_s(const float* __restrict__ p, float s) {
    short8 r;
#pragma unroll
    for (int e = 0; e < 8; ++e) r[e] = (short)f2bf(p[e] * s);
    return r;
}
// sigma2 gather (k-slot (lg,e) <-> col (e>>2)*16 + lg*4 + (e&3)) with scale
__device__ __forceinline__ short8 ldfrag_s2_s(const float* __restrict__ p, int lg, float s) {
    short8 r;
#pragma unroll
    for (int e = 0; e < 8; ++e) r[e] = (short)f2bf(p[(e >> 2) * 16 + lg * 4 + (e & 3)] * s);
    return r;
}

// ===========================================================================
// K1-dual: layer-1 BOTH directions concurrently. 128 blocks x 256 thr.
// Even blocks: forward -> arch_f; odd: reverse -> arch_r. Weights prescaled
// by -log2e (gates i,f,o) / -2log2e (gate g) at fragment load.
// ROUND-12 VERBATIM (measured ~268 us).
// ===========================================================================
__global__ __launch_bounds__(256, 1) void l1dual_kernel(
    const float* __restrict__ x,
    const float* __restrict__ whh1f, const float* __restrict__ wih1f, const float* __restrict__ b1f,
    const float* __restrict__ whh1r, const float* __restrict__ wih1r, const float* __restrict__ b1r,
    unsigned short* __restrict__ arch_f, unsigned short* __restrict__ arch_r)
{
    __shared__ __align__(16) float xT[T_STEPS][20];
    __shared__ __align__(16) short hT[2][16][72];

    const int blk = blockIdx.x;
    const int dir = blk & 1;            // 0 = fwd, 1 = rev
    const int tile = blk >> 1;
    const int tid = threadIdx.x;
    const int wv = tid >> 6, l = tid & 63, lg = l >> 4, lr = l & 15;

    const float* __restrict__ whh = dir ? whh1r : whh1f;
    const float* __restrict__ wih = dir ? wih1r : wih1f;
    const float* __restrict__ bbp = dir ? b1r : b1f;
    unsigned short* __restrict__ archb =
        (dir ? arch_r : arch_f) + (size_t)tile * T_STEPS * 16 * 64;

    for (int i = tid; i < T_STEPS * 16; i += 256) {
        const int b = i >> 9, t = i & 511;
        xT[t][b] = x[(size_t)(tile * 16 + b) * T_STEPS + t];
    }
    for (int i = tid; i < 2 * 16 * 72; i += 256) ((short*)hT)[i] = 0;

    short8 BW[8]; float wihv[4], bvv[4];
#pragma unroll
    for (int g = 0; g < 4; ++g) {
        const float sf = (g == 2) ? 2.0f * NL2E : NL2E;
        const int row = g * 64 + wv * 16 + lr;
        BW[2 * g]     = ldfrag_lin_s(whh + row * 64 + lg * 8, sf);
        BW[2 * g + 1] = ldfrag_lin_s(whh + row * 64 + 32 + lg * 8, sf);
        wihv[g] = wih[row] * sf; bvv[g] = bbp[row] * sf;
    }
    float cst[4] = {0.f, 0.f, 0.f, 0.f};
    __syncthreads();

    for (int i = 0; i < T_STEPS; ++i) {
        const int t = dir ? (T_STEPS - 1 - i) : i;
        const int rp = (t + 1) & 1;     // parity of previous step (both dirs)
        const short8 a0 = *(const short8*)&hT[rp][lr][lg * 8];
        const short8 a1 = *(const short8*)&hT[rp][lr][32 + lg * 8];
        f32x4 z[4];
#pragma unroll
        for (int g = 0; g < 4; ++g) {
            f32x4 za = {0.f, 0.f, 0.f, 0.f}, zb = {0.f, 0.f, 0.f, 0.f};
            za = MFMA16(a0, BW[2 * g], za);
            zb = MFMA16(a1, BW[2 * g + 1], zb);
            z[g] = za + zb;
        }
        const float4 x4v = *(const float4*)&xT[t][lg * 4];
        const float xa[4] = {x4v.x, x4v.y, x4v.z, x4v.w};
#pragma unroll
        for (int j = 0; j < 4; ++j) {
            const float vi = psig (z[0][j] + fmaf(xa[j], wihv[0], bvv[0]));
            const float vf = psig (z[1][j] + fmaf(xa[j], wihv[1], bvv[1]));
            const float vg = ptanh(z[2][j] + fmaf(xa[j], wihv[2], bvv[2]));
            const float vo = psig (z[3][j] + fmaf(xa[j], wihv[3], bvv[3]));
            cst[j] = fmaf(vf, cst[j], vi * vg);
            const float h = vo * tanh_c(cst[j]);
            const unsigned short hb = f2bf(h);
            hT[t & 1][lg * 4 + j][wv * 16 + lr] = (short)hb;
            archb[((size_t)t * 16 + lg * 4 + j) * 64 + wv * 16 + lr] = hb;
        }
        lds_barrier();
    }
}

// ===========================================================================
// K2: layer-2 forward + rev step + head, ONE WAVE per 16-batch tile.
// ROUND-13 VERBATIM (measured ~450 us; the round-14 zpre pipeline REGRESSED
// to 631 us -> reverted). 8 gate-major M-tiles; per step 8x5 C-chained MFMA
// (bias folded into C-init) + 8 gate-evals/lane; h2 B-frag rebuilt in-lane
// (sigma2); hf/hr 2-step-ahead prefetch. NO barrier, NO LDS.
// ===========================================================================
__global__ __launch_bounds__(64, 1) void l2wave_kernel(
    const float* __restrict__ wih2f, const float* __restrict__ whh2f, const float* __restrict__ b2f,
    const float* __restrict__ wih2r, const float* __restrict__ b2r,
    const float* __restrict__ w_fc1, const float* __restrict__ b_fc1,
    const float* __restrict__ w_out, const float* __restrict__ b_out,
    const unsigned short* __restrict__ arch_f, const unsigned short* __restrict__ arch_r,
    float* __restrict__ out)
{
    const int bt = blockIdx.x;
    const int l = threadIdx.x, lg = l >> 4, lr = l & 15;
    const unsigned short* __restrict__ af = arch_f + (size_t)bt * T_STEPS * 16 * 64;
    const unsigned short* __restrict__ ar = arch_r + (size_t)bt * T_STEPS * 16 * 64;

    short8 AF[8][4];   // wih2f: [m][0]=hf k0-31, [1]=hf k32-63, [2]=hr k0-31, [3]=hr k32-63
    short8 A2[8];      // whh2f (sigma2)
    f32x4 bz[8];       // bias as C-init
#pragma unroll
    for (int m = 0; m < 8; ++m) {
        const float sf = ((m >> 1) == 2) ? 2.0f * NL2E : NL2E;
        const int row = m * 16 + lr;
        AF[m][0] = ldfrag_lin_s(wih2f + row * 128 + lg * 8, sf);
        AF[m][1] = ldfrag_lin_s(wih2f + row * 128 + 32 + lg * 8, sf);
        AF[m][2] = ldfrag_lin_s(wih2f + row * 128 + 64 + lg * 8, sf);
        AF[m][3] = ldfrag_lin_s(wih2f + row * 128 + 96 + lg * 8, sf);
        A2[m]    = ldfrag_s2_s(whh2f + row * 32, lg, sf);
#pragma unroll
        for (int j = 0; j < 4; ++j) bz[m][j] = b2f[m * 16 + 4 * lg + j] * sf;
    }

    // 2-step-ahead prefetch, two register sets (A = step s, B = step s+1)
    short8 fA0 = *(const short8*)(af + (size_t)lr * 64 + lg * 8);
    short8 fA1 = *(const short8*)(af + (size_t)lr * 64 + 32 + lg * 8);
    short8 rA0 = *(const short8*)(ar + (size_t)lr * 64 + lg * 8);
    short8 rA1 = *(const short8*)(ar + (size_t)lr * 64 + 32 + lg * 8);
    short8 fB0 = *(const short8*)(af + (size_t)(16 + lr) * 64 + lg * 8);
    short8 fB1 = *(const short8*)(af + (size_t)(16 + lr) * 64 + 32 + lg * 8);
    short8 rB0 = *(const short8*)(ar + (size_t)(16 + lr) * 64 + lg * 8);
    short8 rB1 = *(const short8*)(ar + (size_t)(16 + lr) * 64 + 32 + lg * 8);

    short8 Bh2 = {0, 0, 0, 0, 0, 0, 0, 0};
    float c2[8];
#pragma unroll
    for (int i = 0; i < 8; ++i) c2[i] = 0.f;

    for (int s = 0; s < T_STEPS; ++s) {
        const short8 f0 = fA0, f1 = fA1, r0 = rA0, r1 = rA1;
        fA0 = fB0; fA1 = fB1; rA0 = rB0; rA1 = rB1;
        if (s + 2 < T_STEPS) {
            const size_t o = (size_t)((s + 2) * 16 + lr) * 64 + lg * 8;
            fB0 = *(const short8*)(af + o);
            fB1 = *(const short8*)(af + o + 32);
            rB0 = *(const short8*)(ar + o);
            rB1 = *(const short8*)(ar + o + 32);
        }
        f32x4 z[8];
#pragma unroll
        for (int m = 0; m < 8; ++m) {
            f32x4 a = bz[m];
            a = MFMA16(AF[m][0], f0, a);
            a = MFMA16(AF[m][1], f1, a);
            a = MFMA16(AF[m][2], r0, a);
            a = MFMA16(AF[m][3], r1, a);
            a = MFMA16(A2[m], Bh2, a);
            z[m] = a;
        }
        unsigned short h2b[2][4];
#pragma unroll
        for (int uh = 0; uh < 2; ++uh) {
#pragma unroll
            for (int j = 0; j < 4; ++j) {
                const float vi = psig (z[uh][j]);
                const float vf = psig (z[2 + uh][j]);
                const float vg = ptanh(z[4 + uh][j]);
                const float vo = psig (z[6 + uh][j]);
                float& cc = c2[uh * 4 + j];
                cc = fmaf(vf, cc, vi * vg);
                h2b[uh][j] = f2bf(vo * tanh_c(cc));
            }
        }
#pragma unroll
        for (int e = 0; e < 8; ++e) Bh2[e] = (short)h2b[e >> 2][e & 3];   // sigma2
    }

    // ===== epilogue (same wave): L2-reverse single step @ T-1 + MLP head ===
    {
        short8 Bb = {0, 0, 0, 0, 0, 0, 0, 0};
        if (lg == 0) Bb[0] = (short)0x3F80;                   // B = [1, 0, ...]
        const size_t oL = (size_t)((T_STEPS - 1) * 16 + lr) * 64 + lg * 8;
        const short8 f0 = *(const short8*)(af + oL);
        const short8 f1 = *(const short8*)(af + oL + 32);
        const short8 r0 = *(const short8*)(ar + oL);
        const short8 r1 = *(const short8*)(ar + oL + 32);
        f32x4 ze[8];
#pragma unroll
        for (int mm = 0; mm < 8; ++mm) {
            const int row = mm * 16 + lr;                     // gate-major LIN rows
            const float sfe = ((mm >> 1) == 2) ? 2.0f * NL2E : NL2E;
            const short8 A0 = ldfrag_lin_s(wih2r + row * 128 + lg * 8, sfe);
            const short8 A1 = ldfrag_lin_s(wih2r + row * 128 + 32 + lg * 8, sfe);
            const short8 A2e = ldfrag_lin_s(wih2r + row * 128 + 64 + lg * 8, sfe);
            const short8 A3 = ldfrag_lin_s(wih2r + row * 128 + 96 + lg * 8, sfe);
            short8 bf = {0, 0, 0, 0, 0, 0, 0, 0};
            if (lg == 0) bf[0] = (short)f2bf(b2r[row] * sfe);
            f32x4 za = {0.f, 0.f, 0.f, 0.f}, zb = {0.f, 0.f, 0.f, 0.f};
            za = MFMA16(A0, f0, za);
            za = MFMA16(A2e, r0, za);
            za = MFMA16(bf, Bb, za);
            zb = MFMA16(A1, f1, zb);
            zb = MFMA16(A3, r1, zb);
            ze[mm] = za + zb;
        }
        short8 BR = {0, 0, 0, 0, 0, 0, 0, 0};   // h2r(511), sigma2
#pragma unroll
        for (int uh = 0; uh < 2; ++uh) {
#pragma unroll
            for (int j = 0; j < 4; ++j) {
                const float vi = psig (ze[uh][j]);            // c0=0: f-gate irrelevant
                const float vg = ptanh(ze[4 + uh][j]);
                const float vo = psig (ze[6 + uh][j]);
                BR[uh * 4 + j] = (short)f2bf(vo * tanh_c(vi * vg));
            }
        }
        // head: both w_fc1 halves sigma2-gathered (Bh2 and BR are sigma2)
        float part = 0.f;
#pragma unroll
        for (int mm = 0; mm < 4; ++mm) {
            const int row = mm * 16 + lr;
            const short8 A0 = ldfrag_s2_s(w_fc1 + row * 64, lg, 1.0f);
            const short8 A1 = ldfrag_s2_s(w_fc1 + row * 64 + 32, lg, 1.0f);
            short8 bf = {0, 0, 0, 0, 0, 0, 0, 0};
            if (lg == 0) bf[0] = (short)f2bf(b_fc1[row]);
            f32x4 a = {0.f, 0.f, 0.f, 0.f};
            a = MFMA16(A0, Bh2, a);   // h2f(511)
            a = MFMA16(A1, BR, a);    // h2r(511)
            a = MFMA16(bf, Bb, a);
#pragma unroll
            for (int j = 0; j < 4; ++j)
                part += fmaxf(a[j], 0.f) * w_out[mm * 16 + lg * 4 + j];
        }
        part += __shfl_xor(part, 16, 64);
        part += __shfl_xor(part, 32, 64);
        if (l < 16) out[bt * 16 + lr] = psig(NL2E * (part + b_out[0]));
    }
}

// ---------------------------------------------------------------------------
extern "C" void kernel_launch(void* const* d_in, const int* in_sizes, int n_in,
                              void* d_out, int out_size, void* d_ws, size_t ws_size,
                              hipStream_t stream) {
    const float* x     = (const float*)d_in[0];
    const float* wih1f = (const float*)d_in[1];
    const float* whh1f = (const float*)d_in[2];
    const float* b1f   = (const float*)d_in[3];
    const float* wih1r = (const float*)d_in[4];
    const float* whh1r = (const float*)d_in[5];
    const float* b1r   = (const float*)d_in[6];
    const float* wih2f = (const float*)d_in[7];
    const float* whh2f = (const float*)d_in[8];
    const float* b2f   = (const float*)d_in[9];
    const float* wih2r = (const float*)d_in[10];
    // d_in[11] = whh2r unused: layer-2 reverse runs exactly one step from zero state
    const float* b2r   = (const float*)d_in[12];
    const float* w_fc1 = (const float*)d_in[13];
    const float* b_fc1 = (const float*)d_in[14];
    const float* w_out = (const float*)d_in[15];
    const float* b_out = (const float*)d_in[16];
    float* out = (float*)d_out;

    // 2 x 64 MB archives [tile][t][batch16][unit64] bf16 (ws >= 128 MB proven).
    unsigned short* arch_f = (unsigned short*)d_ws;
    unsigned short* arch_r = arch_f + (size_t)64 * T_STEPS * 16 * 64;

    l1dual_kernel<<<dim3(128), dim3(256), 0, stream>>>(
        x, whh1f, wih1f, b1f, whh1r, wih1r, b1r, arch_f, arch_r);
    l2wave_kernel<<<dim3(64), dim3(64), 0, stream>>>(
        wih2f, whh2f, b2f, wih2r, b2r,
        w_fc1, b_fc1, w_out, b_out, arch_f, arch_r, out);
}

// Round 16
// 609.087 us; speedup vs baseline: 1.9231x; 1.2354x over previous
//
#include <hip/hip_runtime.h>
#include <hip/hip_bf16.h>
#include <math.h>

#define T_STEPS 512
#define BATCH   1024
#define NL2E    (-1.44269504f)   // -log2(e)

typedef __attribute__((ext_vector_type(8))) short short8;
typedef __attribute__((ext_vector_type(4))) float f32x4;

#define MFMA16(A, B, C) __builtin_amdgcn_mfma_f32_16x16x32_bf16((A), (B), (C), 0, 0, 0)

// LDS-only barrier (round-9-verified safe).
__device__ __forceinline__ void lds_barrier() {
    asm volatile("s_waitcnt lgkmcnt(0)" ::: "memory");
    __builtin_amdgcn_s_barrier();
}

// Prescaled activations: zs = -log2e*z (sigmoid) / -2log2e*z (tanh).
__device__ __forceinline__ float psig(float zs) {
    return __builtin_amdgcn_rcpf(1.0f + __builtin_amdgcn_exp2f(zs));
}
__device__ __forceinline__ float ptanh(float zs) {
    return fmaf(2.0f, __builtin_amdgcn_rcpf(1.0f + __builtin_amdgcn_exp2f(zs)), -1.0f);
}
__device__ __forceinline__ float tanh_c(float c) {   // unprescaled input
    return fmaf(2.0f, __builtin_amdgcn_rcpf(
        1.0f + __builtin_amdgcn_exp2f(2.0f * NL2E * c)), -1.0f);
}
__device__ __forceinline__ unsigned short f2bf(float f) {
    unsigned int u = __float_as_uint(f);
    u += 0x7fffu + ((u >> 16) & 1u);
    return (unsigned short)(u >> 16);
}
// linear k-slot gather with scale folded in before bf16 rounding
__device__ __forceinline__ short8 ldfrag_lin_s(const float* __restrict__ p, float s) {
    short8 r;
#pragma unroll
    for (int e = 0; e < 8; ++e) r[e] = (short)f2bf(p[e] * s);
    return r;
}
// sigma2 gather (k-slot (lg,e) <-> col (e>>2)*16 + lg*4 + (e&3)) with scale
__device__ __forceinline__ short8 ldfrag_s2_s(const float* __restrict__ p, int lg, float s) {
    short8 r;
#pragma unroll
    for (int e = 0; e < 8; ++e) r[e] = (short)f2bf(p[(e >> 2) * 16 + lg * 4 + (e & 3)] * s);
    return r;
}

// ===========================================================================
// K1-dual: layer-1 BOTH directions concurrently. 128 blocks x 256 thr.
// ROUND-12 VERBATIM (measured ~254-268 us).
// ===========================================================================
__global__ __launch_bounds__(256, 1) void l1dual_kernel(
    const float* __restrict__ x,
    const float* __restrict__ whh1f, const float* __restrict__ wih1f, const float* __restrict__ b1f,
    const float* __restrict__ whh1r, const float* __restrict__ wih1r, const float* __restrict__ b1r,
    unsigned short* __restrict__ arch_f, unsigned short* __restrict__ arch_r)
{
    __shared__ __align__(16) float xT[T_STEPS][20];
    __shared__ __align__(16) short hT[2][16][72];

    const int blk = blockIdx.x;
    const int dir = blk & 1;            // 0 = fwd, 1 = rev
    const int tile = blk >> 1;
    const int tid = threadIdx.x;
    const int wv = tid >> 6, l = tid & 63, lg = l >> 4, lr = l & 15;

    const float* __restrict__ whh = dir ? whh1r : whh1f;
    const float* __restrict__ wih = dir ? wih1r : wih1f;
    const float* __restrict__ bbp = dir ? b1r : b1f;
    unsigned short* __restrict__ archb =
        (dir ? arch_r : arch_f) + (size_t)tile * T_STEPS * 16 * 64;

    for (int i = tid; i < T_STEPS * 16; i += 256) {
        const int b = i >> 9, t = i & 511;
        xT[t][b] = x[(size_t)(tile * 16 + b) * T_STEPS + t];
    }
    for (int i = tid; i < 2 * 16 * 72; i += 256) ((short*)hT)[i] = 0;

    short8 BW[8]; float wihv[4], bvv[4];
#pragma unroll
    for (int g = 0; g < 4; ++g) {
        const float sf = (g == 2) ? 2.0f * NL2E : NL2E;
        const int row = g * 64 + wv * 16 + lr;
        BW[2 * g]     = ldfrag_lin_s(whh + row * 64 + lg * 8, sf);
        BW[2 * g + 1] = ldfrag_lin_s(whh + row * 64 + 32 + lg * 8, sf);
        wihv[g] = wih[row] * sf; bvv[g] = bbp[row] * sf;
    }
    float cst[4] = {0.f, 0.f, 0.f, 0.f};
    __syncthreads();

    for (int i = 0; i < T_STEPS; ++i) {
        const int t = dir ? (T_STEPS - 1 - i) : i;
        const int rp = (t + 1) & 1;     // parity of previous step (both dirs)
        const short8 a0 = *(const short8*)&hT[rp][lr][lg * 8];
        const short8 a1 = *(const short8*)&hT[rp][lr][32 + lg * 8];
        f32x4 z[4];
#pragma unroll
        for (int g = 0; g < 4; ++g) {
            f32x4 za = {0.f, 0.f, 0.f, 0.f}, zb = {0.f, 0.f, 0.f, 0.f};
            za = MFMA16(a0, BW[2 * g], za);
            zb = MFMA16(a1, BW[2 * g + 1], zb);
            z[g] = za + zb;
        }
        const float4 x4v = *(const float4*)&xT[t][lg * 4];
        const float xa[4] = {x4v.x, x4v.y, x4v.z, x4v.w};
#pragma unroll
        for (int j = 0; j < 4; ++j) {
            const float vi = psig (z[0][j] + fmaf(xa[j], wihv[0], bvv[0]));
            const float vf = psig (z[1][j] + fmaf(xa[j], wihv[1], bvv[1]));
            const float vg = ptanh(z[2][j] + fmaf(xa[j], wihv[2], bvv[2]));
            const float vo = psig (z[3][j] + fmaf(xa[j], wihv[3], bvv[3]));
            cst[j] = fmaf(vf, cst[j], vi * vg);
            const float h = vo * tanh_c(cst[j]);
            const unsigned short hb = f2bf(h);
            hT[t & 1][lg * 4 + j][wv * 16 + lr] = (short)hb;
            archb[((size_t)t * 16 + lg * 4 + j) * 64 + wv * 16 + lr] = hb;
        }
        lds_barrier();
    }
}

// ===========================================================================
// K2: layer-2 via PRODUCER/CONSUMER wave specialization. 64 blocks x 192 thr
// (3 waves). Waves 0-1 (producers): zpre(s) = bz + Wih2f.[hf(s);hr(s)] --
// depends only on the archives, parallel over t; 4 m-tiles each, filled into
// a 128 KB LDS ring (chunks of 8 steps, double-buffered). Wave 2 (consumer):
// per step only z[m] = MFMA(A2[m], Bh2, zpre[m]) + lane-local gates (the
// serial recurrence). Summation order identical to round-13 l2wave (producer
// runs the first 4 C-chained MFMAs, consumer appends the 5th). Barrier only
// at chunk boundaries (65 total). Epilogue (rev step @ T-1 + head) on the
// consumer wave, round-13 verbatim.
// ===========================================================================
__global__ __launch_bounds__(192, 1) void l2pc_kernel(
    const float* __restrict__ wih2f, const float* __restrict__ whh2f, const float* __restrict__ b2f,
    const float* __restrict__ wih2r, const float* __restrict__ b2r,
    const float* __restrict__ w_fc1, const float* __restrict__ b_fc1,
    const float* __restrict__ w_out, const float* __restrict__ b_out,
    const unsigned short* __restrict__ arch_f, const unsigned short* __restrict__ arch_r,
    float* __restrict__ out)
{
    __shared__ __align__(16) float4 zpreL[2][8][8][64];   // 128 KB ring

    const int bt = blockIdx.x, tid = threadIdx.x;
    const int wv = tid >> 6, l = tid & 63, lg = l >> 4, lr = l & 15;
    const unsigned short* __restrict__ af = arch_f + (size_t)bt * T_STEPS * 16 * 64;
    const unsigned short* __restrict__ ar = arch_r + (size_t)bt * T_STEPS * 16 * 64;

    if (wv < 2) {
        // ---------------- producers: m-tiles wv*4 .. wv*4+3 ----------------
        short8 AF[4][4]; f32x4 bz[4];
#pragma unroll
        for (int mi = 0; mi < 4; ++mi) {
            const int m = wv * 4 + mi;
            const float sf = ((m >> 1) == 2) ? 2.0f * NL2E : NL2E;
            const int row = m * 16 + lr;
            AF[mi][0] = ldfrag_lin_s(wih2f + row * 128 + lg * 8, sf);
            AF[mi][1] = ldfrag_lin_s(wih2f + row * 128 + 32 + lg * 8, sf);
            AF[mi][2] = ldfrag_lin_s(wih2f + row * 128 + 64 + lg * 8, sf);
            AF[mi][3] = ldfrag_lin_s(wih2f + row * 128 + 96 + lg * 8, sf);
#pragma unroll
            for (int j = 0; j < 4; ++j) bz[mi][j] = b2f[m * 16 + 4 * lg + j] * sf;
        }
        auto FILL = [&](int cc) {
#pragma unroll 2
            for (int ss = 0; ss < 8; ++ss) {
                const int s = cc * 8 + ss;
                const size_t o = (size_t)(s * 16 + lr) * 64 + lg * 8;
                const short8 f0 = *(const short8*)(af + o);
                const short8 f1 = *(const short8*)(af + o + 32);
                const short8 r0 = *(const short8*)(ar + o);
                const short8 r1 = *(const short8*)(ar + o + 32);
#pragma unroll
                for (int mi = 0; mi < 4; ++mi) {
                    f32x4 a = bz[mi];
                    a = MFMA16(AF[mi][0], f0, a);
                    a = MFMA16(AF[mi][1], f1, a);
                    a = MFMA16(AF[mi][2], r0, a);
                    a = MFMA16(AF[mi][3], r1, a);
                    zpreL[cc & 1][ss][wv * 4 + mi][l] =
                        make_float4(a[0], a[1], a[2], a[3]);
                }
            }
        };
        FILL(0);
        lds_barrier();
        for (int c = 0; c < T_STEPS / 8; ++c) {
            if (c + 1 < T_STEPS / 8) FILL(c + 1);
            lds_barrier();
        }
    } else {
        // ---------------- consumer: serial recurrence ----------------------
        short8 A2[8];
#pragma unroll
        for (int m = 0; m < 8; ++m) {
            const float sf = ((m >> 1) == 2) ? 2.0f * NL2E : NL2E;
            A2[m] = ldfrag_s2_s(whh2f + (m * 16 + lr) * 32, lg, sf);
        }
        short8 Bh2 = {0, 0, 0, 0, 0, 0, 0, 0};
        float c2[8];
#pragma unroll
        for (int i = 0; i < 8; ++i) c2[i] = 0.f;

        lds_barrier();   // matches producers' prologue barrier
        for (int c = 0; c < T_STEPS / 8; ++c) {
#pragma unroll 2
            for (int ss = 0; ss < 8; ++ss) {
                f32x4 z[8];
#pragma unroll
                for (int m = 0; m < 8; ++m) {
                    const f32x4 zp = *(const f32x4*)&zpreL[c & 1][ss][m][l];
                    z[m] = MFMA16(A2[m], Bh2, zp);
                }
                unsigned short h2b[2][4];
#pragma unroll
                for (int uh = 0; uh < 2; ++uh) {
#pragma unroll
                    for (int j = 0; j < 4; ++j) {
                        const float vi = psig (z[uh][j]);
                        const float vf = psig (z[2 + uh][j]);
                        const float vg = ptanh(z[4 + uh][j]);
                        const float vo = psig (z[6 + uh][j]);
                        float& cc2 = c2[uh * 4 + j];
                        cc2 = fmaf(vf, cc2, vi * vg);
                        h2b[uh][j] = f2bf(vo * tanh_c(cc2));
                    }
                }
#pragma unroll
                for (int e = 0; e < 8; ++e) Bh2[e] = (short)h2b[e >> 2][e & 3];
            }
            lds_barrier();
        }

        // ===== epilogue: L2-reverse single step @ T-1 + MLP head ===========
        short8 Bb = {0, 0, 0, 0, 0, 0, 0, 0};
        if (lg == 0) Bb[0] = (short)0x3F80;                   // B = [1, 0, ...]
        const size_t oL = (size_t)((T_STEPS - 1) * 16 + lr) * 64 + lg * 8;
        const short8 f0 = *(const short8*)(af + oL);
        const short8 f1 = *(const short8*)(af + oL + 32);
        const short8 r0 = *(const short8*)(ar + oL);
        const short8 r1 = *(const short8*)(ar + oL + 32);
        f32x4 ze[8];
#pragma unroll
        for (int mm = 0; mm < 8; ++mm) {
            const int row = mm * 16 + lr;                     // gate-major LIN rows
            const float sfe = ((mm >> 1) == 2) ? 2.0f * NL2E : NL2E;
            const short8 A0 = ldfrag_lin_s(wih2r + row * 128 + lg * 8, sfe);
            const short8 A1 = ldfrag_lin_s(wih2r + row * 128 + 32 + lg * 8, sfe);
            const short8 A2e = ldfrag_lin_s(wih2r + row * 128 + 64 + lg * 8, sfe);
            const short8 A3 = ldfrag_lin_s(wih2r + row * 128 + 96 + lg * 8, sfe);
            short8 bf = {0, 0, 0, 0, 0, 0, 0, 0};
            if (lg == 0) bf[0] = (short)f2bf(b2r[row] * sfe);
            f32x4 za = {0.f, 0.f, 0.f, 0.f}, zb = {0.f, 0.f, 0.f, 0.f};
            za = MFMA16(A0, f0, za);
            za = MFMA16(A2e, r0, za);
            za = MFMA16(bf, Bb, za);
            zb = MFMA16(A1, f1, zb);
            zb = MFMA16(A3, r1, zb);
            ze[mm] = za + zb;
        }
        short8 BR = {0, 0, 0, 0, 0, 0, 0, 0};   // h2r(511), sigma2
#pragma unroll
        for (int uh = 0; uh < 2; ++uh) {
#pragma unroll
            for (int j = 0; j < 4; ++j) {
                const float vi = psig (ze[uh][j]);            // c0=0: f-gate irrelevant
                const float vg = ptanh(ze[4 + uh][j]);
                const float vo = psig (ze[6 + uh][j]);
                BR[uh * 4 + j] = (short)f2bf(vo * tanh_c(vi * vg));
            }
        }
        float part = 0.f;
#pragma unroll
        for (int mm = 0; mm < 4; ++mm) {
            const int row = mm * 16 + lr;
            const short8 A0 = ldfrag_s2_s(w_fc1 + row * 64, lg, 1.0f);
            const short8 A1 = ldfrag_s2_s(w_fc1 + row * 64 + 32, lg, 1.0f);
            short8 bf = {0, 0, 0, 0, 0, 0, 0, 0};
            if (lg == 0) bf[0] = (short)f2bf(b_fc1[row]);
            f32x4 a = {0.f, 0.f, 0.f, 0.f};
            a = MFMA16(A0, Bh2, a);   // h2f(511)
            a = MFMA16(A1, BR, a);    // h2r(511)
            a = MFMA16(bf, Bb, a);
#pragma unroll
            for (int j = 0; j < 4; ++j)
                part += fmaxf(a[j], 0.f) * w_out[mm * 16 + lg * 4 + j];
        }
        part += __shfl_xor(part, 16, 64);
        part += __shfl_xor(part, 32, 64);
        if (l < 16) out[bt * 16 + lr] = psig(NL2E * (part + b_out[0]));
    }
}

// ---------------------------------------------------------------------------
extern "C" void kernel_launch(void* const* d_in, const int* in_sizes, int n_in,
                              void* d_out, int out_size, void* d_ws, size_t ws_size,
                              hipStream_t stream) {
    const float* x     = (const float*)d_in[0];
    const float* wih1f = (const float*)d_in[1];
    const float* whh1f = (const float*)d_in[2];
    const float* b1f   = (const float*)d_in[3];
    const float* wih1r = (const float*)d_in[4];
    const float* whh1r = (const float*)d_in[5];
    const float* b1r   = (const float*)d_in[6];
    const float* wih2f = (const float*)d_in[7];
    const float* whh2f = (const float*)d_in[8];
    const float* b2f   = (const float*)d_in[9];
    const float* wih2r = (const float*)d_in[10];
    // d_in[11] = whh2r unused: layer-2 reverse runs exactly one step from zero state
    const float* b2r   = (const float*)d_in[12];
    const float* w_fc1 = (const float*)d_in[13];
    const float* b_fc1 = (const float*)d_in[14];
    const float* w_out = (const float*)d_in[15];
    const float* b_out = (const float*)d_in[16];
    float* out = (float*)d_out;

    // 2 x 64 MB archives [tile][t][batch16][unit64] bf16 (ws >= 128 MB proven).
    unsigned short* arch_f = (unsigned short*)d_ws;
    unsigned short* arch_r = arch_f + (size_t)64 * T_STEPS * 16 * 64;

    l1dual_kernel<<<dim3(128), dim3(256), 0, stream>>>(
        x, whh1f, wih1f, b1f, whh1r, wih1r, b1r, arch_f, arch_r);
    l2pc_kernel<<<dim3(64), dim3(192), 0, stream>>>(
        wih2f, whh2f, b2f, wih2r, b2r,
        w_fc1, b_fc1, w_out, b_out, arch_f, arch_r, out);
}

// Round 17
// 550.200 us; speedup vs baseline: 2.1289x; 1.1070x over previous
//
#include <hip/hip_runtime.h>
#include <hip/hip_bf16.h>
#include <math.h>

#define T_STEPS 512
#define BATCH   1024
#define NL2E    (-1.44269504f)   // -log2(e)

typedef __attribute__((ext_vector_type(8))) short short8;
typedef __attribute__((ext_vector_type(4))) float f32x4;

#define MFMA16(A, B, C) __builtin_amdgcn_mfma_f32_16x16x32_bf16((A), (B), (C), 0, 0, 0)

// LDS-only barrier (round-9-verified safe).
__device__ __forceinline__ void lds_barrier() {
    asm volatile("s_waitcnt lgkmcnt(0)" ::: "memory");
    __builtin_amdgcn_s_barrier();
}

// Prescaled activations: zs = -log2e*z (sigmoid) / -2log2e*z (tanh).
__device__ __forceinline__ float psig(float zs) {
    return __builtin_amdgcn_rcpf(1.0f + __builtin_amdgcn_exp2f(zs));
}
__device__ __forceinline__ float ptanh(float zs) {
    return fmaf(2.0f, __builtin_amdgcn_rcpf(1.0f + __builtin_amdgcn_exp2f(zs)), -1.0f);
}
__device__ __forceinline__ float tanh_c(float c) {   // unprescaled input
    return fmaf(2.0f, __builtin_amdgcn_rcpf(
        1.0f + __builtin_amdgcn_exp2f(2.0f * NL2E * c)), -1.0f);
}
__device__ __forceinline__ unsigned short f2bf(float f) {
    unsigned int u = __float_as_uint(f);
    u += 0x7fffu + ((u >> 16) & 1u);
    return (unsigned short)(u >> 16);
}
// linear k-slot gather with scale folded in before bf16 rounding
__device__ __forceinline__ short8 ldfrag_lin_s(const float* __restrict__ p, float s) {
    short8 r;
#pragma unroll
    for (int e = 0; e < 8; ++e) r[e] = (short)f2bf(p[e] * s);
    return r;
}
// sigma2 gather (k-slot (lg,e) <-> col (e>>2)*16 + lg*4 + (e&3)) with scale
__device__ __forceinline__ short8 ldfrag_s2_s(const float* __restrict__ p, int lg, float s) {
    short8 r;
#pragma unroll
    for (int e = 0; e < 8; ++e) r[e] = (short)f2bf(p[(e >> 2) * 16 + lg * 4 + (e & 3)] * s);
    return r;
}

// ===========================================================================
// K1-dual: layer-1 BOTH directions concurrently. 128 blocks x 256 thr.
// ROUND-12 VERBATIM (measured ~254-268 us).
// ===========================================================================
__global__ __launch_bounds__(256, 1) void l1dual_kernel(
    const float* __restrict__ x,
    const float* __restrict__ whh1f, const float* __restrict__ wih1f, const float* __restrict__ b1f,
    const float* __restrict__ whh1r, const float* __restrict__ wih1r, const float* __restrict__ b1r,
    unsigned short* __restrict__ arch_f, unsigned short* __restrict__ arch_r)
{
    __shared__ __align__(16) float xT[T_STEPS][20];
    __shared__ __align__(16) short hT[2][16][72];

    const int blk = blockIdx.x;
    const int dir = blk & 1;            // 0 = fwd, 1 = rev
    const int tile = blk >> 1;
    const int tid = threadIdx.x;
    const int wv = tid >> 6, l = tid & 63, lg = l >> 4, lr = l & 15;

    const float* __restrict__ whh = dir ? whh1r : whh1f;
    const float* __restrict__ wih = dir ? wih1r : wih1f;
    const float* __restrict__ bbp = dir ? b1r : b1f;
    unsigned short* __restrict__ archb =
        (dir ? arch_r : arch_f) + (size_t)tile * T_STEPS * 16 * 64;

    for (int i = tid; i < T_STEPS * 16; i += 256) {
        const int b = i >> 9, t = i & 511;
        xT[t][b] = x[(size_t)(tile * 16 + b) * T_STEPS + t];
    }
    for (int i = tid; i < 2 * 16 * 72; i += 256) ((short*)hT)[i] = 0;

    short8 BW[8]; float wihv[4], bvv[4];
#pragma unroll
    for (int g = 0; g < 4; ++g) {
        const float sf = (g == 2) ? 2.0f * NL2E : NL2E;
        const int row = g * 64 + wv * 16 + lr;
        BW[2 * g]     = ldfrag_lin_s(whh + row * 64 + lg * 8, sf);
        BW[2 * g + 1] = ldfrag_lin_s(whh + row * 64 + 32 + lg * 8, sf);
        wihv[g] = wih[row] * sf; bvv[g] = bbp[row] * sf;
    }
    float cst[4] = {0.f, 0.f, 0.f, 0.f};
    __syncthreads();

    for (int i = 0; i < T_STEPS; ++i) {
        const int t = dir ? (T_STEPS - 1 - i) : i;
        const int rp = (t + 1) & 1;     // parity of previous step (both dirs)
        const short8 a0 = *(const short8*)&hT[rp][lr][lg * 8];
        const short8 a1 = *(const short8*)&hT[rp][lr][32 + lg * 8];
        f32x4 z[4];
#pragma unroll
        for (int g = 0; g < 4; ++g) {
            f32x4 za = {0.f, 0.f, 0.f, 0.f}, zb = {0.f, 0.f, 0.f, 0.f};
            za = MFMA16(a0, BW[2 * g], za);
            zb = MFMA16(a1, BW[2 * g + 1], zb);
            z[g] = za + zb;
        }
        const float4 x4v = *(const float4*)&xT[t][lg * 4];
        const float xa[4] = {x4v.x, x4v.y, x4v.z, x4v.w};
#pragma unroll
        for (int j = 0; j < 4; ++j) {
            const float vi = psig (z[0][j] + fmaf(xa[j], wihv[0], bvv[0]));
            const float vf = psig (z[1][j] + fmaf(xa[j], wihv[1], bvv[1]));
            const float vg = ptanh(z[2][j] + fmaf(xa[j], wihv[2], bvv[2]));
            const float vo = psig (z[3][j] + fmaf(xa[j], wihv[3], bvv[3]));
            cst[j] = fmaf(vf, cst[j], vi * vg);
            const float h = vo * tanh_c(cst[j]);
            const unsigned short hb = f2bf(h);
            hT[t & 1][lg * 4 + j][wv * 16 + lr] = (short)hb;
            archb[((size_t)t * 16 + lg * 4 + j) * 64 + wv * 16 + lr] = hb;
        }
        lds_barrier();
    }
}

// ===========================================================================
// K2: layer-2, producer/consumer + SPLIT CONSUMER. 64 blocks x 256 thr.
// Waves 0-1 (producers, round-16 verbatim): zpre = bz + Wih2f.[hf;hr] into a
// 128 KB LDS ring, chunks of 8 steps, chunk barriers only.
// Waves 2-3 (consumers): C0 = even m-tiles (units 0-15), C1 = odd (16-31),
// each 4 MFMA + 40 trans per step on its OWN SIMD's trans pipe. h2 halves
// exchanged per-lane via LDS uint2 + monotone flag + s_sleep spin (NOT
// s_barrier; producers stay decoupled). Data double-buffered by step parity:
// slot overwritten 2 steps later, by which time the partner has provably
// consumed it (its flag(s+1) required our data(s)). Epilogue on C0.
// ===========================================================================
__global__ __launch_bounds__(256, 1) void l2pc_kernel(
    const float* __restrict__ wih2f, const float* __restrict__ whh2f, const float* __restrict__ b2f,
    const float* __restrict__ wih2r, const float* __restrict__ b2r,
    const float* __restrict__ w_fc1, const float* __restrict__ b_fc1,
    const float* __restrict__ w_out, const float* __restrict__ b_out,
    const unsigned short* __restrict__ arch_f, const unsigned short* __restrict__ arch_r,
    float* __restrict__ out)
{
    __shared__ __align__(16) float4 zpreL[2][8][8][64];   // 128 KB ring
    __shared__ __align__(8)  uint2  exD[2][2][64];        // [cw][parity][lane]
    __shared__ int exFlag[2];

    const int bt = blockIdx.x, tid = threadIdx.x;
    const int wv = tid >> 6, l = tid & 63, lg = l >> 4, lr = l & 15;
    const unsigned short* __restrict__ af = arch_f + (size_t)bt * T_STEPS * 16 * 64;
    const unsigned short* __restrict__ ar = arch_r + (size_t)bt * T_STEPS * 16 * 64;

    if (tid < 2) exFlag[tid] = 0;

    if (wv < 2) {
        // ---------------- producers: m-tiles wv*4 .. wv*4+3 ----------------
        short8 AF[4][4]; f32x4 bz[4];
#pragma unroll
        for (int mi = 0; mi < 4; ++mi) {
            const int m = wv * 4 + mi;
            const float sf = ((m >> 1) == 2) ? 2.0f * NL2E : NL2E;
            const int row = m * 16 + lr;
            AF[mi][0] = ldfrag_lin_s(wih2f + row * 128 + lg * 8, sf);
            AF[mi][1] = ldfrag_lin_s(wih2f + row * 128 + 32 + lg * 8, sf);
            AF[mi][2] = ldfrag_lin_s(wih2f + row * 128 + 64 + lg * 8, sf);
            AF[mi][3] = ldfrag_lin_s(wih2f + row * 128 + 96 + lg * 8, sf);
#pragma unroll
            for (int j = 0; j < 4; ++j) bz[mi][j] = b2f[m * 16 + 4 * lg + j] * sf;
        }
        auto FILL = [&](int cc) {
#pragma unroll 2
            for (int ss = 0; ss < 8; ++ss) {
                const int s = cc * 8 + ss;
                const size_t o = (size_t)(s * 16 + lr) * 64 + lg * 8;
                const short8 f0 = *(const short8*)(af + o);
                const short8 f1 = *(const short8*)(af + o + 32);
                const short8 r0 = *(const short8*)(ar + o);
                const short8 r1 = *(const short8*)(ar + o + 32);
#pragma unroll
                for (int mi = 0; mi < 4; ++mi) {
                    f32x4 a = bz[mi];
                    a = MFMA16(AF[mi][0], f0, a);
                    a = MFMA16(AF[mi][1], f1, a);
                    a = MFMA16(AF[mi][2], r0, a);
                    a = MFMA16(AF[mi][3], r1, a);
                    zpreL[cc & 1][ss][wv * 4 + mi][l] =
                        make_float4(a[0], a[1], a[2], a[3]);
                }
            }
        };
        FILL(0);
        lds_barrier();
        for (int c = 0; c < T_STEPS / 8; ++c) {
            if (c + 1 < T_STEPS / 8) FILL(c + 1);
            lds_barrier();
        }
    } else {
        // ---------------- split consumers ----------------------------------
        const int cw = wv - 2;          // 0: even tiles (units 0-15), 1: odd
        short8 A2[4];
#pragma unroll
        for (int g = 0; g < 4; ++g) {
            const int m = 2 * g + cw;
            const float sf = (g == 2) ? 2.0f * NL2E : NL2E;
            A2[g] = ldfrag_s2_s(whh2f + (m * 16 + lr) * 32, lg, sf);
        }
        short8 Bh2 = {0, 0, 0, 0, 0, 0, 0, 0};
        float c2[4] = {0.f, 0.f, 0.f, 0.f};
        volatile int* myf = (volatile int*)&exFlag[cw];
        volatile int* otf = (volatile int*)&exFlag[cw ^ 1];

        lds_barrier();   // matches producers' prologue barrier
        int s = 0;
        for (int c = 0; c < T_STEPS / 8; ++c) {
#pragma unroll 2
            for (int ss = 0; ss < 8; ++ss, ++s) {
                f32x4 z[4];
#pragma unroll
                for (int g = 0; g < 4; ++g) {
                    const f32x4 zp = *(const f32x4*)&zpreL[c & 1][ss][2 * g + cw][l];
                    z[g] = MFMA16(A2[g], Bh2, zp);
                }
                unsigned short hb[4];
#pragma unroll
                for (int j = 0; j < 4; ++j) {
                    const float vi = psig (z[0][j]);
                    const float vf = psig (z[1][j]);
                    const float vg = ptanh(z[2][j]);
                    const float vo = psig (z[3][j]);
                    c2[j] = fmaf(vf, c2[j], vi * vg);
                    hb[j] = f2bf(vo * tanh_c(c2[j]));
                }
                uint2 own;
                own.x = (unsigned)hb[0] | ((unsigned)hb[1] << 16);
                own.y = (unsigned)hb[2] | ((unsigned)hb[3] << 16);
                exD[cw][s & 1][l] = own;
                asm volatile("s_waitcnt lgkmcnt(0)" ::: "memory");
                if (l == 0) *myf = s + 1;
                while (*otf <= s) __builtin_amdgcn_s_sleep(1);
                asm volatile("" ::: "memory");
                const uint2 oth = exD[cw ^ 1][s & 1][l];
                const uint2 lo = cw ? oth : own;   // units 0-15
                const uint2 hi = cw ? own : oth;   // units 16-31
                Bh2[0] = (short)(lo.x);
                Bh2[1] = (short)(lo.x >> 16);
                Bh2[2] = (short)(lo.y);
                Bh2[3] = (short)(lo.y >> 16);
                Bh2[4] = (short)(hi.x);
                Bh2[5] = (short)(hi.x >> 16);
                Bh2[6] = (short)(hi.y);
                Bh2[7] = (short)(hi.y >> 16);
            }
            lds_barrier();
        }

        // ===== epilogue (C0 only): L2-reverse single step @ T-1 + head =====
        if (cw == 0) {
            short8 Bb = {0, 0, 0, 0, 0, 0, 0, 0};
            if (lg == 0) Bb[0] = (short)0x3F80;               // B = [1, 0, ...]
            const size_t oL = (size_t)((T_STEPS - 1) * 16 + lr) * 64 + lg * 8;
            const short8 f0 = *(const short8*)(af + oL);
            const short8 f1 = *(const short8*)(af + oL + 32);
            const short8 r0 = *(const short8*)(ar + oL);
            const short8 r1 = *(const short8*)(ar + oL + 32);
            f32x4 ze[8];
#pragma unroll
            for (int mm = 0; mm < 8; ++mm) {
                const int row = mm * 16 + lr;                 // gate-major LIN rows
                const float sfe = ((mm >> 1) == 2) ? 2.0f * NL2E : NL2E;
                const short8 A0 = ldfrag_lin_s(wih2r + row * 128 + lg * 8, sfe);
                const short8 A1 = ldfrag_lin_s(wih2r + row * 128 + 32 + lg * 8, sfe);
                const short8 A2e = ldfrag_lin_s(wih2r + row * 128 + 64 + lg * 8, sfe);
                const short8 A3 = ldfrag_lin_s(wih2r + row * 128 + 96 + lg * 8, sfe);
                short8 bf = {0, 0, 0, 0, 0, 0, 0, 0};
                if (lg == 0) bf[0] = (short)f2bf(b2r[row] * sfe);
                f32x4 za = {0.f, 0.f, 0.f, 0.f}, zb = {0.f, 0.f, 0.f, 0.f};
                za = MFMA16(A0, f0, za);
                za = MFMA16(A2e, r0, za);
                za = MFMA16(bf, Bb, za);
                zb = MFMA16(A1, f1, zb);
                zb = MFMA16(A3, r1, zb);
                ze[mm] = za + zb;
            }
            short8 BR = {0, 0, 0, 0, 0, 0, 0, 0};   // h2r(511), sigma2
#pragma unroll
            for (int uh = 0; uh < 2; ++uh) {
#pragma unroll
                for (int j = 0; j < 4; ++j) {
                    const float vi = psig (ze[uh][j]);        // c0=0: f-gate irrelevant
                    const float vg = ptanh(ze[4 + uh][j]);
                    const float vo = psig (ze[6 + uh][j]);
                    BR[uh * 4 + j] = (short)f2bf(vo * tanh_c(vi * vg));
                }
            }
            float part = 0.f;
#pragma unroll
            for (int mm = 0; mm < 4; ++mm) {
                const int row = mm * 16 + lr;
                const short8 A0 = ldfrag_s2_s(w_fc1 + row * 64, lg, 1.0f);
                const short8 A1 = ldfrag_s2_s(w_fc1 + row * 64 + 32, lg, 1.0f);
                short8 bf = {0, 0, 0, 0, 0, 0, 0, 0};
                if (lg == 0) bf[0] = (short)f2bf(b_fc1[row]);
                f32x4 a = {0.f, 0.f, 0.f, 0.f};
                a = MFMA16(A0, Bh2, a);   // h2f(511), full (post-exchange)
                a = MFMA16(A1, BR, a);    // h2r(511)
                a = MFMA16(bf, Bb, a);
#pragma unroll
                for (int j = 0; j < 4; ++j)
                    part += fmaxf(a[j], 0.f) * w_out[mm * 16 + lg * 4 + j];
            }
            part += __shfl_xor(part, 16, 64);
            part += __shfl_xor(part, 32, 64);
            if (l < 16) out[bt * 16 + lr] = psig(NL2E * (part + b_out[0]));
        }
    }
}

// ---------------------------------------------------------------------------
extern "C" void kernel_launch(void* const* d_in, const int* in_sizes, int n_in,
                              void* d_out, int out_size, void* d_ws, size_t ws_size,
                              hipStream_t stream) {
    const float* x     = (const float*)d_in[0];
    const float* wih1f = (const float*)d_in[1];
    const float* whh1f = (const float*)d_in[2];
    const float* b1f   = (const float*)d_in[3];
    const float* wih1r = (const float*)d_in[4];
    const float* whh1r = (const float*)d_in[5];
    const float* b1r   = (const float*)d_in[6];
    const float* wih2f = (const float*)d_in[7];
    const float* whh2f = (const float*)d_in[8];
    const float* b2f   = (const float*)d_in[9];
    const float* wih2r = (const float*)d_in[10];
    // d_in[11] = whh2r unused: layer-2 reverse runs exactly one step from zero state
    const float* b2r   = (const float*)d_in[12];
    const float* w_fc1 = (const float*)d_in[13];
    const float* b_fc1 = (const float*)d_in[14];
    const float* w_out = (const float*)d_in[15];
    const float* b_out = (const float*)d_in[16];
    float* out = (float*)d_out;

    // 2 x 64 MB archives [tile][t][batch16][unit64] bf16 (ws >= 128 MB proven).
    unsigned short* arch_f = (unsigned short*)d_ws;
    unsigned short* arch_r = arch_f + (size_t)64 * T_STEPS * 16 * 64;

    l1dual_kernel<<<dim3(128), dim3(256), 0, stream>>>(
        x, whh1f, wih1f, b1f, whh1r, wih1r, b1r, arch_f, arch_r);
    l2pc_kernel<<<dim3(64), dim3(256), 0, stream>>>(
        wih2f, whh2f, b2f, wih2r, b2r,
        w_fc1, b_fc1, w_out, b_out, arch_f, arch_r, out);
}

// Round 18
// 514.006 us; speedup vs baseline: 2.2788x; 1.0704x over previous
//
#include <hip/hip_runtime.h>
#include <hip/hip_bf16.h>
#include <math.h>

#define T_STEPS 512
#define BATCH   1024
#define NL2E    (-1.44269504f)   // -log2(e)

typedef __attribute__((ext_vector_type(8))) short short8;
typedef __attribute__((ext_vector_type(4))) float f32x4;

#define MFMA16(A, B, C) __builtin_amdgcn_mfma_f32_16x16x32_bf16((A), (B), (C), 0, 0, 0)

// LDS-only barrier (round-9-verified safe).
__device__ __forceinline__ void lds_barrier() {
    asm volatile("s_waitcnt lgkmcnt(0)" ::: "memory");
    __builtin_amdgcn_s_barrier();
}

// Prescaled activations: zs = -log2e*z (sigmoid) / -2log2e*z (tanh).
__device__ __forceinline__ float psig(float zs) {
    return __builtin_amdgcn_rcpf(1.0f + __builtin_amdgcn_exp2f(zs));
}
__device__ __forceinline__ float ptanh(float zs) {
    return fmaf(2.0f, __builtin_amdgcn_rcpf(1.0f + __builtin_amdgcn_exp2f(zs)), -1.0f);
}
__device__ __forceinline__ float tanh_c(float c) {   // unprescaled input
    return fmaf(2.0f, __builtin_amdgcn_rcpf(
        1.0f + __builtin_amdgcn_exp2f(2.0f * NL2E * c)), -1.0f);
}
__device__ __forceinline__ unsigned short f2bf(float f) {
    unsigned int u = __float_as_uint(f);
    u += 0x7fffu + ((u >> 16) & 1u);
    return (unsigned short)(u >> 16);
}
// linear k-slot gather with scale folded in before bf16 rounding
__device__ __forceinline__ short8 ldfrag_lin_s(const float* __restrict__ p, float s) {
    short8 r;
#pragma unroll
    for (int e = 0; e < 8; ++e) r[e] = (short)f2bf(p[e] * s);
    return r;
}
// sigma2 gather (k-slot (lg,e) <-> col (e>>2)*16 + lg*4 + (e&3)) with scale
__device__ __forceinline__ short8 ldfrag_s2_s(const float* __restrict__ p, int lg, float s) {
    short8 r;
#pragma unroll
    for (int e = 0; e < 8; ++e) r[e] = (short)f2bf(p[(e >> 2) * 16 + lg * 4 + (e & 3)] * s);
    return r;
}

// ===========================================================================
// K1-oct: layer-1 both directions, 128 blocks (tile,dir) x 512 thr (8 waves,
// 2 waves/SIMD). Interleaved-row mapping (l2top-style, A = WEIGHTS):
// tile q of wave wv has M-row r -> gate (r&3), unit wv*8 + (r>>2)*2 + q, so
// lane (lg,lr)'s C values z[j] are the 4 GATES of (unit wv*8+2lg+q, batch lr)
// -> 2 lane-local c-updates = 20 trans/lane/step (was 40: halves the
// trans-latency chain per wave; per-SIMD issue unchanged). The lane's two
// units are ADJACENT -> h + archive writes stay packed as single uints.
// ===========================================================================
__global__ __launch_bounds__(512, 1) void l1oct_kernel(
    const float* __restrict__ x,
    const float* __restrict__ whh1f, const float* __restrict__ wih1f, const float* __restrict__ b1f,
    const float* __restrict__ whh1r, const float* __restrict__ wih1r, const float* __restrict__ b1r,
    unsigned short* __restrict__ arch_f, unsigned short* __restrict__ arch_r)
{
    __shared__ __align__(16) float xT[T_STEPS][20];
    __shared__ __align__(16) short hT[2][16][72];

    const int blk = blockIdx.x;
    const int dir = blk & 1;            // 0 = fwd, 1 = rev
    const int tile = blk >> 1;
    const int tid = threadIdx.x;
    const int wv = tid >> 6, l = tid & 63, lg = l >> 4, lr = l & 15;

    const float* __restrict__ whh = dir ? whh1r : whh1f;
    const float* __restrict__ wih = dir ? wih1r : wih1f;
    const float* __restrict__ bbp = dir ? b1r : b1f;
    unsigned short* __restrict__ archb =
        (dir ? arch_r : arch_f) + (size_t)tile * T_STEPS * 16 * 64;

    for (int i = tid; i < T_STEPS * 16; i += 512) {
        const int b = i >> 9, t = i & 511;
        xT[t][b] = x[(size_t)(tile * 16 + b) * T_STEPS + t];
    }
    for (int i = tid; i < 2 * 16 * 72; i += 512) ((short*)hT)[i] = 0;

    // A-frags: weight row orow_q(lr) = (lr&3)*64 + wv*8 + (lr>>2)*2 + q,
    // k = units (LIN). Per-lane row scale keyed off gate = lr&3.
    const float sfl = ((lr & 3) == 2) ? 2.0f * NL2E : NL2E;
    short8 AW[2][2];
    float wihv[2][4], bvv[2][4];
#pragma unroll
    for (int q = 0; q < 2; ++q) {
        const int orow = (lr & 3) * 64 + wv * 8 + (lr >> 2) * 2 + q;
        AW[q][0] = ldfrag_lin_s(whh + orow * 64, sfl);
        AW[q][1] = ldfrag_lin_s(whh + orow * 64 + 32, sfl);
        const int u0 = wv * 8 + 2 * lg + q;     // this lane's unit for tile q
#pragma unroll
        for (int j = 0; j < 4; ++j) {
            const float sfj = (j == 2) ? 2.0f * NL2E : NL2E;
            wihv[q][j] = wih[j * 64 + u0] * sfj;
            bvv[q][j]  = bbp[j * 64 + u0] * sfj;
        }
    }
    float cst[2] = {0.f, 0.f};
    const int u0 = wv * 8 + 2 * lg;             // even unit (q=0); q=1 is u0+1
    __syncthreads();

    for (int i = 0; i < T_STEPS; ++i) {
        const int t = dir ? (T_STEPS - 1 - i) : i;
        const int rp = (t + 1) & 1;             // parity of previous step
        // B-frags: h(t-1), column = batch lr, k = units (LIN)
        const short8 b0 = *(const short8*)&hT[rp][lr][lg * 8];
        const short8 b1 = *(const short8*)&hT[rp][lr][32 + lg * 8];
        f32x4 z[2];
#pragma unroll
        for (int q = 0; q < 2; ++q) {
            f32x4 za = {0.f, 0.f, 0.f, 0.f}, zb = {0.f, 0.f, 0.f, 0.f};
            za = MFMA16(AW[q][0], b0, za);
            zb = MFMA16(AW[q][1], b1, zb);
            z[q] = za + zb;
        }
        const float xt = xT[t][lr];
        unsigned short hq[2];
#pragma unroll
        for (int q = 0; q < 2; ++q) {
            const float vi = psig (z[q][0] + fmaf(xt, wihv[q][0], bvv[q][0]));
            const float vf = psig (z[q][1] + fmaf(xt, wihv[q][1], bvv[q][1]));
            const float vg = ptanh(z[q][2] + fmaf(xt, wihv[q][2], bvv[q][2]));
            const float vo = psig (z[q][3] + fmaf(xt, wihv[q][3], bvv[q][3]));
            cst[q] = fmaf(vf, cst[q], vi * vg);
            hq[q] = f2bf(vo * tanh_c(cst[q]));
        }
        const unsigned int hv = (unsigned)hq[0] | ((unsigned)hq[1] << 16);
        *(unsigned int*)&hT[t & 1][lr][u0] = hv;                    // units u0,u0+1
        *(unsigned int*)(archb + ((size_t)t * 16 + lr) * 64 + u0) = hv;
        lds_barrier();
    }
}

// ===========================================================================
// K2: layer-2, producer/consumer + split consumer. ROUND-17 VERBATIM
// (measured ~255 us).
// ===========================================================================
__global__ __launch_bounds__(256, 1) void l2pc_kernel(
    const float* __restrict__ wih2f, const float* __restrict__ whh2f, const float* __restrict__ b2f,
    const float* __restrict__ wih2r, const float* __restrict__ b2r,
    const float* __restrict__ w_fc1, const float* __restrict__ b_fc1,
    const float* __restrict__ w_out, const float* __restrict__ b_out,
    const unsigned short* __restrict__ arch_f, const unsigned short* __restrict__ arch_r,
    float* __restrict__ out)
{
    __shared__ __align__(16) float4 zpreL[2][8][8][64];   // 128 KB ring
    __shared__ __align__(8)  uint2  exD[2][2][64];        // [cw][parity][lane]
    __shared__ int exFlag[2];

    const int bt = blockIdx.x, tid = threadIdx.x;
    const int wv = tid >> 6, l = tid & 63, lg = l >> 4, lr = l & 15;
    const unsigned short* __restrict__ af = arch_f + (size_t)bt * T_STEPS * 16 * 64;
    const unsigned short* __restrict__ ar = arch_r + (size_t)bt * T_STEPS * 16 * 64;

    if (tid < 2) exFlag[tid] = 0;

    if (wv < 2) {
        short8 AF[4][4]; f32x4 bz[4];
#pragma unroll
        for (int mi = 0; mi < 4; ++mi) {
            const int m = wv * 4 + mi;
            const float sf = ((m >> 1) == 2) ? 2.0f * NL2E : NL2E;
            const int row = m * 16 + lr;
            AF[mi][0] = ldfrag_lin_s(wih2f + row * 128 + lg * 8, sf);
            AF[mi][1] = ldfrag_lin_s(wih2f + row * 128 + 32 + lg * 8, sf);
            AF[mi][2] = ldfrag_lin_s(wih2f + row * 128 + 64 + lg * 8, sf);
            AF[mi][3] = ldfrag_lin_s(wih2f + row * 128 + 96 + lg * 8, sf);
#pragma unroll
            for (int j = 0; j < 4; ++j) bz[mi][j] = b2f[m * 16 + 4 * lg + j] * sf;
        }
        auto FILL = [&](int cc) {
#pragma unroll 2
            for (int ss = 0; ss < 8; ++ss) {
                const int s = cc * 8 + ss;
                const size_t o = (size_t)(s * 16 + lr) * 64 + lg * 8;
                const short8 f0 = *(const short8*)(af + o);
                const short8 f1 = *(const short8*)(af + o + 32);
                const short8 r0 = *(const short8*)(ar + o);
                const short8 r1 = *(const short8*)(ar + o + 32);
#pragma unroll
                for (int mi = 0; mi < 4; ++mi) {
                    f32x4 a = bz[mi];
                    a = MFMA16(AF[mi][0], f0, a);
                    a = MFMA16(AF[mi][1], f1, a);
                    a = MFMA16(AF[mi][2], r0, a);
                    a = MFMA16(AF[mi][3], r1, a);
                    zpreL[cc & 1][ss][wv * 4 + mi][l] =
                        make_float4(a[0], a[1], a[2], a[3]);
                }
            }
        };
        FILL(0);
        lds_barrier();
        for (int c = 0; c < T_STEPS / 8; ++c) {
            if (c + 1 < T_STEPS / 8) FILL(c + 1);
            lds_barrier();
        }
    } else {
        const int cw = wv - 2;          // 0: even tiles (units 0-15), 1: odd
        short8 A2[4];
#pragma unroll
        for (int g = 0; g < 4; ++g) {
            const int m = 2 * g + cw;
            const float sf = (g == 2) ? 2.0f * NL2E : NL2E;
            A2[g] = ldfrag_s2_s(whh2f + (m * 16 + lr) * 32, lg, sf);
        }
        short8 Bh2 = {0, 0, 0, 0, 0, 0, 0, 0};
        float c2[4] = {0.f, 0.f, 0.f, 0.f};
        volatile int* myf = (volatile int*)&exFlag[cw];
        volatile int* otf = (volatile int*)&exFlag[cw ^ 1];

        lds_barrier();   // matches producers' prologue barrier
        int s = 0;
        for (int c = 0; c < T_STEPS / 8; ++c) {
#pragma unroll 2
            for (int ss = 0; ss < 8; ++ss, ++s) {
                f32x4 z[4];
#pragma unroll
                for (int g = 0; g < 4; ++g) {
                    const f32x4 zp = *(const f32x4*)&zpreL[c & 1][ss][2 * g + cw][l];
                    z[g] = MFMA16(A2[g], Bh2, zp);
                }
                unsigned short hb[4];
#pragma unroll
                for (int j = 0; j < 4; ++j) {
                    const float vi = psig (z[0][j]);
                    const float vf = psig (z[1][j]);
                    const float vg = ptanh(z[2][j]);
                    const float vo = psig (z[3][j]);
                    c2[j] = fmaf(vf, c2[j], vi * vg);
                    hb[j] = f2bf(vo * tanh_c(c2[j]));
                }
                uint2 own;
                own.x = (unsigned)hb[0] | ((unsigned)hb[1] << 16);
                own.y = (unsigned)hb[2] | ((unsigned)hb[3] << 16);
                exD[cw][s & 1][l] = own;
                asm volatile("s_waitcnt lgkmcnt(0)" ::: "memory");
                if (l == 0) *myf = s + 1;
                while (*otf <= s) __builtin_amdgcn_s_sleep(1);
                asm volatile("" ::: "memory");
                const uint2 oth = exD[cw ^ 1][s & 1][l];
                const uint2 lo = cw ? oth : own;   // units 0-15
                const uint2 hi = cw ? own : oth;   // units 16-31
                Bh2[0] = (short)(lo.x);
                Bh2[1] = (short)(lo.x >> 16);
                Bh2[2] = (short)(lo.y);
                Bh2[3] = (short)(lo.y >> 16);
                Bh2[4] = (short)(hi.x);
                Bh2[5] = (short)(hi.x >> 16);
                Bh2[6] = (short)(hi.y);
                Bh2[7] = (short)(hi.y >> 16);
            }
            lds_barrier();
        }

        if (cw == 0) {
            short8 Bb = {0, 0, 0, 0, 0, 0, 0, 0};
            if (lg == 0) Bb[0] = (short)0x3F80;               // B = [1, 0, ...]
            const size_t oL = (size_t)((T_STEPS - 1) * 16 + lr) * 64 + lg * 8;
            const short8 f0 = *(const short8*)(af + oL);
            const short8 f1 = *(const short8*)(af + oL + 32);
            const short8 r0 = *(const short8*)(ar + oL);
            const short8 r1 = *(const short8*)(ar + oL + 32);
            f32x4 ze[8];
#pragma unroll
            for (int mm = 0; mm < 8; ++mm) {
                const int row = mm * 16 + lr;                 // gate-major LIN rows
                const float sfe = ((mm >> 1) == 2) ? 2.0f * NL2E : NL2E;
                const short8 A0 = ldfrag_lin_s(wih2r + row * 128 + lg * 8, sfe);
                const short8 A1 = ldfrag_lin_s(wih2r + row * 128 + 32 + lg * 8, sfe);
                const short8 A2e = ldfrag_lin_s(wih2r + row * 128 + 64 + lg * 8, sfe);
                const short8 A3 = ldfrag_lin_s(wih2r + row * 128 + 96 + lg * 8, sfe);
                short8 bf = {0, 0, 0, 0, 0, 0, 0, 0};
                if (lg == 0) bf[0] = (short)f2bf(b2r[row] * sfe);
                f32x4 za = {0.f, 0.f, 0.f, 0.f}, zb = {0.f, 0.f, 0.f, 0.f};
                za = MFMA16(A0, f0, za);
                za = MFMA16(A2e, r0, za);
                za = MFMA16(bf, Bb, za);
                zb = MFMA16(A1, f1, zb);
                zb = MFMA16(A3, r1, zb);
                ze[mm] = za + zb;
            }
            short8 BR = {0, 0, 0, 0, 0, 0, 0, 0};   // h2r(511), sigma2
#pragma unroll
            for (int uh = 0; uh < 2; ++uh) {
#pragma unroll
                for (int j = 0; j < 4; ++j) {
                    const float vi = psig (ze[uh][j]);        // c0=0: f-gate irrelevant
                    const float vg = ptanh(ze[4 + uh][j]);
                    const float vo = psig (ze[6 + uh][j]);
                    BR[uh * 4 + j] = (short)f2bf(vo * tanh_c(vi * vg));
                }
            }
            float part = 0.f;
#pragma unroll
            for (int mm = 0; mm < 4; ++mm) {
                const int row = mm * 16 + lr;
                const short8 A0 = ldfrag_s2_s(w_fc1 + row * 64, lg, 1.0f);
                const short8 A1 = ldfrag_s2_s(w_fc1 + row * 64 + 32, lg, 1.0f);
                short8 bf = {0, 0, 0, 0, 0, 0, 0, 0};
                if (lg == 0) bf[0] = (short)f2bf(b_fc1[row]);
                f32x4 a = {0.f, 0.f, 0.f, 0.f};
                a = MFMA16(A0, Bh2, a);   // h2f(511), full (post-exchange)
                a = MFMA16(A1, BR, a);    // h2r(511)
                a = MFMA16(bf, Bb, a);
#pragma unroll
                for (int j = 0; j < 4; ++j)
                    part += fmaxf(a[j], 0.f) * w_out[mm * 16 + lg * 4 + j];
            }
            part += __shfl_xor(part, 16, 64);
            part += __shfl_xor(part, 32, 64);
            if (l < 16) out[bt * 16 + lr] = psig(NL2E * (part + b_out[0]));
        }
    }
}

// ---------------------------------------------------------------------------
extern "C" void kernel_launch(void* const* d_in, const int* in_sizes, int n_in,
                              void* d_out, int out_size, void* d_ws, size_t ws_size,
                              hipStream_t stream) {
    const float* x     = (const float*)d_in[0];
    const float* wih1f = (const float*)d_in[1];
    const float* whh1f = (const float*)d_in[2];
    const float* b1f   = (const float*)d_in[3];
    const float* wih1r = (const float*)d_in[4];
    const float* whh1r = (const float*)d_in[5];
    const float* b1r   = (const float*)d_in[6];
    const float* wih2f = (const float*)d_in[7];
    const float* whh2f = (const float*)d_in[8];
    const float* b2f   = (const float*)d_in[9];
    const float* wih2r = (const float*)d_in[10];
    // d_in[11] = whh2r unused: layer-2 reverse runs exactly one step from zero state
    const float* b2r   = (const float*)d_in[12];
    const float* w_fc1 = (const float*)d_in[13];
    const float* b_fc1 = (const float*)d_in[14];
    const float* w_out = (const float*)d_in[15];
    const float* b_out = (const float*)d_in[16];
    float* out = (float*)d_out;

    // 2 x 64 MB archives [tile][t][batch16][unit64] bf16 (ws >= 128 MB proven).
    unsigned short* arch_f = (unsigned short*)d_ws;
    unsigned short* arch_r = arch_f + (size_t)64 * T_STEPS * 16 * 64;

    l1oct_kernel<<<dim3(128), dim3(512), 0, stream>>>(
        x, whh1f, wih1f, b1f, whh1r, wih1r, b1r, arch_f, arch_r);
    l2pc_kernel<<<dim3(64), dim3(256), 0, stream>>>(
        wih2f, whh2f, b2f, wih2r, b2r,
        w_fc1, b_fc1, w_out, b_out, arch_f, arch_r, out);
}